// Round 1
// baseline (1849.590 us; speedup 1.0000x reference)
//
#include <hip/hip_runtime.h>
#include <cstdint>
#include <cstddef>

#define NTOK 8192
#define DIM  1024
#define NEXP 64
#define RANK 64
#define NGRP 8
#define NLOC 8

// ---------------------------------------------------------------------------
// Routing: one wave per token. fp32 exact (integer outputs must match np argmax).
// ---------------------------------------------------------------------------
__global__ __launch_bounds__(256) void routing_kernel(
    const float* __restrict__ h, const float* __restrict__ Wg,
    const float* __restrict__ bg, const float* __restrict__ Wloc,
    float* __restrict__ out_eid, float* __restrict__ out_gate,
    float* __restrict__ out_gidx,
    int* __restrict__ ws_eids, float* __restrict__ ws_gates,
    int* __restrict__ counts)
{
    const int wave = threadIdx.x >> 6;
    const int lane = threadIdx.x & 63;
    const int t = blockIdx.x * 4 + wave;

    const float* hrow = h + (size_t)t * DIM;
    float hreg[16];
#pragma unroll
    for (int i = 0; i < 16; ++i) hreg[i] = hrow[i * 64 + lane];

    // stage 1: group scores
    float acc[NGRP];
#pragma unroll
    for (int g = 0; g < NGRP; ++g) acc[g] = 0.f;
#pragma unroll
    for (int i = 0; i < 16; ++i) {
        const int d = i * 64 + lane;
        const float4* wp = (const float4*)(Wg + (size_t)d * NGRP);
        float4 w0 = wp[0], w1 = wp[1];
        const float hd = hreg[i];
        acc[0] += hd * w0.x; acc[1] += hd * w0.y;
        acc[2] += hd * w0.z; acc[3] += hd * w0.w;
        acc[4] += hd * w1.x; acc[5] += hd * w1.y;
        acc[6] += hd * w1.z; acc[7] += hd * w1.w;
    }
#pragma unroll
    for (int g = 0; g < NGRP; ++g) {
#pragma unroll
        for (int s = 32; s >= 1; s >>= 1) acc[g] += __shfl_xor(acc[g], s, 64);
        acc[g] += bg[g];
    }
    // argmax, first-index-wins (matches np/jnp argmax tie rule)
    int gi = 0; float best = acc[0];
#pragma unroll
    for (int g = 1; g < NGRP; ++g) { if (acc[g] > best) { best = acc[g]; gi = g; } }

    // stage 2: within-group scores for the selected group only
    float acc2[NLOC];
#pragma unroll
    for (int m = 0; m < NLOC; ++m) acc2[m] = 0.f;
    const float* wl = Wloc + (size_t)gi * DIM * NLOC;
#pragma unroll
    for (int i = 0; i < 16; ++i) {
        const int d = i * 64 + lane;
        const float4* wp = (const float4*)(wl + (size_t)d * NLOC);
        float4 w0 = wp[0], w1 = wp[1];
        const float hd = hreg[i];
        acc2[0] += hd * w0.x; acc2[1] += hd * w0.y;
        acc2[2] += hd * w0.z; acc2[3] += hd * w0.w;
        acc2[4] += hd * w1.x; acc2[5] += hd * w1.y;
        acc2[6] += hd * w1.z; acc2[7] += hd * w1.w;
    }
#pragma unroll
    for (int m = 0; m < NLOC; ++m) {
#pragma unroll
        for (int s = 32; s >= 1; s >>= 1) acc2[m] += __shfl_xor(acc2[m], s, 64);
    }
    // top-2, first-index-wins on ties (matches lax.top_k stability)
    int m1 = 0; float v1 = acc2[0];
#pragma unroll
    for (int m = 1; m < NLOC; ++m) { if (acc2[m] > v1) { v1 = acc2[m]; m1 = m; } }
    int m2 = (m1 == 0) ? 1 : 0; float v2 = acc2[m2];
#pragma unroll
    for (int m = 0; m < NLOC; ++m) {
        if (m != m1 && m != ((m1 == 0) ? 1 : 0) && acc2[m] > v2) { v2 = acc2[m]; m2 = m; }
    }
    // softmax over [v1, v2], v1 >= v2
    const float e2v = expf(v2 - v1);
    const float inv = 1.f / (1.f + e2v);
    const float g0 = inv, g1 = e2v * inv;
    const int e0 = gi * NLOC + m1, e1 = gi * NLOC + m2;

    if (lane == 0) {
        out_eid[t * 2 + 0] = (float)e0;
        out_eid[t * 2 + 1] = (float)e1;
        out_gate[t * 2 + 0] = g0;
        out_gate[t * 2 + 1] = g1;
        out_gidx[t] = (float)gi;
        ws_eids[t * 2 + 0] = e0;
        ws_eids[t * 2 + 1] = e1;
        ws_gates[t * 2 + 0] = g0;
        ws_gates[t * 2 + 1] = g1;
        atomicAdd(&counts[e0], 1);
        atomicAdd(&counts[e1], 1);
    }
}

// ---------------------------------------------------------------------------
// Exclusive scan over 64 expert counts (single wave).
// ---------------------------------------------------------------------------
__global__ __launch_bounds__(64) void scan_kernel(
    const int* __restrict__ counts, int* __restrict__ offsets, int* __restrict__ cursor)
{
    const int e = threadIdx.x;  // 0..63
    const int c = counts[e];
    int s = c;
#pragma unroll
    for (int d = 1; d < 64; d <<= 1) {
        int v = __shfl_up(s, d, 64);
        if (e >= d) s += v;
    }
    offsets[e] = s - c;
    cursor[e] = s - c;
    if (e == 63) offsets[64] = s;
}

// ---------------------------------------------------------------------------
// Scatter token ids into per-expert buckets.
// ---------------------------------------------------------------------------
__global__ __launch_bounds__(256) void scatter_kernel(
    const int* __restrict__ ws_eids, const float* __restrict__ ws_gates,
    int* __restrict__ cursor, int* __restrict__ token_list, float* __restrict__ slot_gate)
{
    const int t = blockIdx.x * 256 + threadIdx.x;
    if (t >= NTOK) return;
#pragma unroll
    for (int j = 0; j < 2; ++j) {
        const int eid = ws_eids[t * 2 + j];
        const int pos = atomicAdd(&cursor[eid], 1);
        token_list[pos] = t;
        slot_gate[pos] = ws_gates[t * 2 + j];
    }
}

// ---------------------------------------------------------------------------
// E1: P[slot, r] = gate * relu( h[tok] @ W1[e] ).  Tile 64 tokens x 64 R,
// K-chunks of 64, 256 threads, 4x4 register blocking, float4 LDS reads.
// ---------------------------------------------------------------------------
__global__ __launch_bounds__(256) void e1_kernel(
    const float* __restrict__ h, const float* __restrict__ W1,
    const int* __restrict__ offsets, const int* __restrict__ token_list,
    const float* __restrict__ slot_gate, float* __restrict__ P)
{
    __shared__ float HsT[64][68];   // [k][token]
    __shared__ float Ws[64][68];    // [k][r]
    __shared__ int   tokS[64];
    __shared__ float gateS[64];

    const int e = blockIdx.x;
    const int n0 = offsets[e];
    const int ne = offsets[e + 1] - n0;
    const float* W1e = W1 + (size_t)e * DIM * RANK;
    const int tx = threadIdx.x & 15, ty = threadIdx.x >> 4;

    for (int tile = blockIdx.y; tile * 64 < ne; tile += gridDim.y) {
        const int row0 = tile * 64;
        if (threadIdx.x < 64) {
            const int gr = row0 + threadIdx.x;
            tokS[threadIdx.x]  = (gr < ne) ? token_list[n0 + gr] : -1;
            gateS[threadIdx.x] = (gr < ne) ? slot_gate[n0 + gr] : 0.f;
        }
        float acc[4][4] = {};
        for (int kc = 0; kc < DIM; kc += 64) {
            __syncthreads();   // tokS ready (1st iter) / LDS reuse safe
#pragma unroll
            for (int k = 0; k < 16; ++k) {
                const int idx = threadIdx.x + k * 256;
                const int r = idx >> 6, c = idx & 63;
                const int tok = tokS[r];
                HsT[c][r] = (tok >= 0) ? h[(size_t)tok * DIM + kc + c] : 0.f;
                Ws[idx >> 6][idx & 63] = W1e[(size_t)kc * RANK + idx];
            }
            __syncthreads();
#pragma unroll
            for (int k = 0; k < 64; ++k) {
                const float4 a = *(const float4*)&HsT[k][ty * 4];
                const float4 b = *(const float4*)&Ws[k][tx * 4];
                const float av[4] = {a.x, a.y, a.z, a.w};
                const float bv[4] = {b.x, b.y, b.z, b.w};
#pragma unroll
                for (int i = 0; i < 4; ++i)
#pragma unroll
                    for (int j = 0; j < 4; ++j) acc[i][j] += av[i] * bv[j];
            }
        }
#pragma unroll
        for (int i = 0; i < 4; ++i) {
            const int gr = row0 + ty * 4 + i;
            if (gr < ne) {
                const float gt = gateS[ty * 4 + i];
                float4 v;
                v.x = fmaxf(acc[i][0], 0.f) * gt;
                v.y = fmaxf(acc[i][1], 0.f) * gt;
                v.z = fmaxf(acc[i][2], 0.f) * gt;
                v.w = fmaxf(acc[i][3], 0.f) * gt;
                *(float4*)&P[(size_t)(n0 + gr) * RANK + tx * 4] = v;
            }
        }
        __syncthreads();   // protect tokS/gateS before next tile overwrites
    }
}

// ---------------------------------------------------------------------------
// E2: out[tok] += P[slot] @ W2[e].  Tile 64 tokens x 128 cols (two 64-halves),
// K=64 in one shot, 4x(4+4) register blocking, atomicAdd into out.
// ---------------------------------------------------------------------------
__global__ __launch_bounds__(256) void e2_kernel(
    const float* __restrict__ P, const float* __restrict__ W2,
    const int* __restrict__ offsets, const int* __restrict__ token_list,
    float* __restrict__ out)
{
    __shared__ float PsT[64][68];    // [k][token]
    __shared__ float W2s[64][132];   // [k][col 0..127]
    __shared__ int   tokS[64];

    const int e = blockIdx.x;
    const int colbase = blockIdx.y * 128;
    const int n0 = offsets[e];
    const int ne = offsets[e + 1] - n0;
    const float* W2e = W2 + (size_t)e * RANK * DIM;
    const int tx = threadIdx.x & 15, ty = threadIdx.x >> 4;

    // W2 tile: loaded once per block (K=64 total)
#pragma unroll
    for (int k = 0; k < 32; ++k) {
        const int idx = threadIdx.x + k * 256;      // 0..8191
        const int r = idx >> 7, c = idx & 127;
        W2s[r][c] = W2e[(size_t)r * DIM + colbase + c];
    }

    for (int tile = blockIdx.z; tile * 64 < ne; tile += gridDim.z) {
        const int row0 = tile * 64;
        __syncthreads();   // W2s ready (1st iter) / previous tile done
        if (threadIdx.x < 64) {
            const int gr = row0 + threadIdx.x;
            tokS[threadIdx.x] = (gr < ne) ? token_list[n0 + gr] : -1;
        }
#pragma unroll
        for (int k = 0; k < 16; ++k) {
            const int idx = threadIdx.x + k * 256;
            const int r = idx >> 6, c = idx & 63;
            const int gr = row0 + r;
            PsT[c][r] = (gr < ne) ? P[(size_t)(n0 + gr) * RANK + c] : 0.f;
        }
        __syncthreads();
        float acc[4][8] = {};
#pragma unroll
        for (int k = 0; k < 64; ++k) {
            const float4 a  = *(const float4*)&PsT[k][ty * 4];
            const float4 b0 = *(const float4*)&W2s[k][tx * 4];
            const float4 b1 = *(const float4*)&W2s[k][64 + tx * 4];
            const float av[4] = {a.x, a.y, a.z, a.w};
            const float bv[8] = {b0.x, b0.y, b0.z, b0.w, b1.x, b1.y, b1.z, b1.w};
#pragma unroll
            for (int i = 0; i < 4; ++i)
#pragma unroll
                for (int j = 0; j < 8; ++j) acc[i][j] += av[i] * bv[j];
        }
#pragma unroll
        for (int i = 0; i < 4; ++i) {
            const int tok = tokS[ty * 4 + i];
            if (tok >= 0) {
                float* op = out + (size_t)tok * DIM + colbase;
#pragma unroll
                for (int j = 0; j < 4; ++j) atomicAdd(op + tx * 4 + j, acc[i][j]);
#pragma unroll
                for (int j = 0; j < 4; ++j) atomicAdd(op + 64 + tx * 4 + j, acc[i][4 + j]);
            }
        }
    }
}

// ---------------------------------------------------------------------------
extern "C" void kernel_launch(void* const* d_in, const int* in_sizes, int n_in,
                              void* d_out, int out_size, void* d_ws, size_t ws_size,
                              hipStream_t stream)
{
    const float* h    = (const float*)d_in[0];
    const float* Wg   = (const float*)d_in[1];
    const float* bg   = (const float*)d_in[2];
    const float* Wloc = (const float*)d_in[3];
    const float* W1   = (const float*)d_in[4];
    const float* W2   = (const float*)d_in[5];
    // d_in[6] = k (constant 2 for this problem)

    float* out_f    = (float*)d_out;
    float* out_main = out_f;                               // (N, D)
    float* out_eid  = out_f + (size_t)NTOK * DIM;          // (N, 2) as floats
    float* out_gate = out_eid + (size_t)NTOK * 2;          // (N, 2)
    float* out_gidx = out_gate + (size_t)NTOK * 2;         // (N,)  as floats

    int* ws_i        = (int*)d_ws;
    int* counts      = ws_i;                 // 64
    int* offsets     = ws_i + 64;            // 65
    int* cursor      = ws_i + 192;           // 64
    int* ws_eids     = ws_i + 256;           // 16384
    int* token_list  = ws_i + 256 + 16384;   // 16384
    float* ws_f      = (float*)(ws_i + 256 + 2 * 16384);
    float* ws_gates  = ws_f;                 // 16384
    float* slot_gate = ws_f + 16384;         // 16384
    float* P         = ws_f + 2 * 16384;     // 16384*64 = 4 MB

    hipMemsetAsync(counts, 0, 64 * sizeof(int), stream);
    hipMemsetAsync(out_main, 0, (size_t)NTOK * DIM * sizeof(float), stream);

    routing_kernel<<<NTOK / 4, 256, 0, stream>>>(h, Wg, bg, Wloc,
        out_eid, out_gate, out_gidx, ws_eids, ws_gates, counts);
    scan_kernel<<<1, 64, 0, stream>>>(counts, offsets, cursor);
    scatter_kernel<<<NTOK / 256, 256, 0, stream>>>(ws_eids, ws_gates, cursor,
        token_list, slot_gate);
    e1_kernel<<<dim3(NEXP, 8), 256, 0, stream>>>(h, W1, offsets, token_list,
        slot_gate, P);
    e2_kernel<<<dim3(NEXP, 8, 2), 256, 0, stream>>>(P, W2, offsets, token_list,
        out_main);
}

// Round 2
// 1343.854 us; speedup vs baseline: 1.3763x; 1.3763x over previous
//
#include <hip/hip_runtime.h>
#include <cstdint>
#include <cstddef>

#define NTOK 8192
#define DIM  1024
#define NEXP 64
#define RANK 64
#define NGRP 8
#define NLOC 8

// ---------------------------------------------------------------------------
// Routing: one wave per token. fp32 exact (integer outputs must match np argmax).
// ---------------------------------------------------------------------------
__global__ __launch_bounds__(256) void routing_kernel(
    const float* __restrict__ h, const float* __restrict__ Wg,
    const float* __restrict__ bg, const float* __restrict__ Wloc,
    float* __restrict__ out_eid, float* __restrict__ out_gate,
    float* __restrict__ out_gidx,
    int* __restrict__ ws_eids, float* __restrict__ ws_gates,
    int* __restrict__ counts)
{
    const int wave = threadIdx.x >> 6;
    const int lane = threadIdx.x & 63;
    const int t = blockIdx.x * 4 + wave;

    const float* hrow = h + (size_t)t * DIM;
    float hreg[16];
#pragma unroll
    for (int i = 0; i < 16; ++i) hreg[i] = hrow[i * 64 + lane];

    // stage 1: group scores
    float acc[NGRP];
#pragma unroll
    for (int g = 0; g < NGRP; ++g) acc[g] = 0.f;
#pragma unroll
    for (int i = 0; i < 16; ++i) {
        const int d = i * 64 + lane;
        const float4* wp = (const float4*)(Wg + (size_t)d * NGRP);
        float4 w0 = wp[0], w1 = wp[1];
        const float hd = hreg[i];
        acc[0] += hd * w0.x; acc[1] += hd * w0.y;
        acc[2] += hd * w0.z; acc[3] += hd * w0.w;
        acc[4] += hd * w1.x; acc[5] += hd * w1.y;
        acc[6] += hd * w1.z; acc[7] += hd * w1.w;
    }
#pragma unroll
    for (int g = 0; g < NGRP; ++g) {
#pragma unroll
        for (int s = 32; s >= 1; s >>= 1) acc[g] += __shfl_xor(acc[g], s, 64);
        acc[g] += bg[g];
    }
    // argmax, first-index-wins (matches np/jnp argmax tie rule)
    int gi = 0; float best = acc[0];
#pragma unroll
    for (int g = 1; g < NGRP; ++g) { if (acc[g] > best) { best = acc[g]; gi = g; } }

    // stage 2: within-group scores for the selected group only
    float acc2[NLOC];
#pragma unroll
    for (int m = 0; m < NLOC; ++m) acc2[m] = 0.f;
    const float* wl = Wloc + (size_t)gi * DIM * NLOC;
#pragma unroll
    for (int i = 0; i < 16; ++i) {
        const int d = i * 64 + lane;
        const float4* wp = (const float4*)(wl + (size_t)d * NLOC);
        float4 w0 = wp[0], w1 = wp[1];
        const float hd = hreg[i];
        acc2[0] += hd * w0.x; acc2[1] += hd * w0.y;
        acc2[2] += hd * w0.z; acc2[3] += hd * w0.w;
        acc2[4] += hd * w1.x; acc2[5] += hd * w1.y;
        acc2[6] += hd * w1.z; acc2[7] += hd * w1.w;
    }
#pragma unroll
    for (int m = 0; m < NLOC; ++m) {
#pragma unroll
        for (int s = 32; s >= 1; s >>= 1) acc2[m] += __shfl_xor(acc2[m], s, 64);
    }
    // top-2, first-index-wins on ties (matches lax.top_k stability)
    int m1 = 0; float v1 = acc2[0];
#pragma unroll
    for (int m = 1; m < NLOC; ++m) { if (acc2[m] > v1) { v1 = acc2[m]; m1 = m; } }
    int m2 = (m1 == 0) ? 1 : 0; float v2 = acc2[m2];
#pragma unroll
    for (int m = 0; m < NLOC; ++m) {
        if (m != m1 && m != ((m1 == 0) ? 1 : 0) && acc2[m] > v2) { v2 = acc2[m]; m2 = m; }
    }
    // softmax over [v1, v2], v1 >= v2
    const float e2v = expf(v2 - v1);
    const float inv = 1.f / (1.f + e2v);
    const float g0 = inv, g1 = e2v * inv;
    const int e0 = gi * NLOC + m1, e1 = gi * NLOC + m2;

    if (lane == 0) {
        out_eid[t * 2 + 0] = (float)e0;
        out_eid[t * 2 + 1] = (float)e1;
        out_gate[t * 2 + 0] = g0;
        out_gate[t * 2 + 1] = g1;
        out_gidx[t] = (float)gi;
        ws_eids[t * 2 + 0] = e0;
        ws_eids[t * 2 + 1] = e1;
        ws_gates[t * 2 + 0] = g0;
        ws_gates[t * 2 + 1] = g1;
        atomicAdd(&counts[e0], 1);
        atomicAdd(&counts[e1], 1);
    }
}

// ---------------------------------------------------------------------------
// Exclusive scan over 64 expert counts (single wave).
// ---------------------------------------------------------------------------
__global__ __launch_bounds__(64) void scan_kernel(
    const int* __restrict__ counts, int* __restrict__ offsets, int* __restrict__ cursor)
{
    const int e = threadIdx.x;  // 0..63
    const int c = counts[e];
    int s = c;
#pragma unroll
    for (int d = 1; d < 64; d <<= 1) {
        int v = __shfl_up(s, d, 64);
        if (e >= d) s += v;
    }
    offsets[e] = s - c;
    cursor[e] = s - c;
    if (e == 63) offsets[64] = s;
}

// ---------------------------------------------------------------------------
// Scatter token ids into per-expert buckets. Entry encodes (token, slot-rank):
// entry = tok*2 + j, j in {0,1}. j=0 slots later write out directly (unique
// per token); j=1 slots write the contrib scratch. No output atomics anywhere.
// ---------------------------------------------------------------------------
__global__ __launch_bounds__(256) void scatter_kernel(
    const int* __restrict__ ws_eids, const float* __restrict__ ws_gates,
    int* __restrict__ cursor, int* __restrict__ token_list, float* __restrict__ slot_gate)
{
    const int t = blockIdx.x * 256 + threadIdx.x;
    if (t >= NTOK) return;
#pragma unroll
    for (int j = 0; j < 2; ++j) {
        const int eid = ws_eids[t * 2 + j];
        const int pos = atomicAdd(&cursor[eid], 1);
        token_list[pos] = t * 2 + j;
        slot_gate[pos] = ws_gates[t * 2 + j];
    }
}

// ---------------------------------------------------------------------------
// E1: P[slot, r] = gate * relu( h[tok] @ W1[e] ).  Tile 64 slots x 64 R,
// K-chunks of 64, 256 threads, 4x4 register blocking, float4 LDS reads.
// ---------------------------------------------------------------------------
__global__ __launch_bounds__(256) void e1_kernel(
    const float* __restrict__ h, const float* __restrict__ W1,
    const int* __restrict__ offsets, const int* __restrict__ token_list,
    const float* __restrict__ slot_gate, float* __restrict__ P)
{
    __shared__ float HsT[64][68];   // [k][slot]
    __shared__ float Ws[64][68];    // [k][r]
    __shared__ int   tokS[64];      // entry = tok*2+j, or -1 pad
    __shared__ float gateS[64];

    const int e = blockIdx.x;
    const int n0 = offsets[e];
    const int ne = offsets[e + 1] - n0;
    const float* W1e = W1 + (size_t)e * DIM * RANK;
    const int tx = threadIdx.x & 15, ty = threadIdx.x >> 4;

    for (int tile = blockIdx.y; tile * 64 < ne; tile += gridDim.y) {
        const int row0 = tile * 64;
        if (threadIdx.x < 64) {
            const int gr = row0 + threadIdx.x;
            tokS[threadIdx.x]  = (gr < ne) ? token_list[n0 + gr] : -1;
            gateS[threadIdx.x] = (gr < ne) ? slot_gate[n0 + gr] : 0.f;
        }
        float acc[4][4] = {};
        for (int kc = 0; kc < DIM; kc += 64) {
            __syncthreads();   // tokS ready (1st iter) / LDS reuse safe
#pragma unroll
            for (int k = 0; k < 16; ++k) {
                const int idx = threadIdx.x + k * 256;
                const int r = idx >> 6, c = idx & 63;
                const int ent = tokS[r];
                HsT[c][r] = (ent >= 0) ? h[(size_t)(ent >> 1) * DIM + kc + c] : 0.f;
                Ws[idx >> 6][idx & 63] = W1e[(size_t)kc * RANK + idx];
            }
            __syncthreads();
#pragma unroll
            for (int k = 0; k < 64; ++k) {
                const float4 a = *(const float4*)&HsT[k][ty * 4];
                const float4 b = *(const float4*)&Ws[k][tx * 4];
                const float av[4] = {a.x, a.y, a.z, a.w};
                const float bv[4] = {b.x, b.y, b.z, b.w};
#pragma unroll
                for (int i = 0; i < 4; ++i)
#pragma unroll
                    for (int j = 0; j < 4; ++j) acc[i][j] += av[i] * bv[j];
            }
        }
#pragma unroll
        for (int i = 0; i < 4; ++i) {
            const int gr = row0 + ty * 4 + i;
            if (gr < ne) {
                const float gt = gateS[ty * 4 + i];
                float4 v;
                v.x = fmaxf(acc[i][0], 0.f) * gt;
                v.y = fmaxf(acc[i][1], 0.f) * gt;
                v.z = fmaxf(acc[i][2], 0.f) * gt;
                v.w = fmaxf(acc[i][3], 0.f) * gt;
                *(float4*)&P[(size_t)(n0 + gr) * RANK + tx * 4] = v;
            }
        }
        __syncthreads();   // protect tokS/gateS before next tile overwrites
    }
}

// ---------------------------------------------------------------------------
// E2: C_slot = P[slot] @ W2[e].  Tile 64 slots x 128 cols, K=64 in one shot,
// 4x(4+4) register blocking. j=0 slots STORE to out[tok] (unique per token);
// j=1 slots STORE to contrib[tok]. Zero atomics.
// ---------------------------------------------------------------------------
__global__ __launch_bounds__(256) void e2_kernel(
    const float* __restrict__ P, const float* __restrict__ W2,
    const int* __restrict__ offsets, const int* __restrict__ token_list,
    float* __restrict__ out, float* __restrict__ contrib)
{
    __shared__ float PsT[64][68];    // [k][slot]
    __shared__ float W2s[64][132];   // [k][col 0..127]
    __shared__ int   tokS[64];

    const int e = blockIdx.x;
    const int colbase = blockIdx.y * 128;
    const int n0 = offsets[e];
    const int ne = offsets[e + 1] - n0;
    const float* W2e = W2 + (size_t)e * RANK * DIM;
    const int tx = threadIdx.x & 15, ty = threadIdx.x >> 4;

    // W2 tile: loaded once per block (K=64 total)
#pragma unroll
    for (int k = 0; k < 32; ++k) {
        const int idx = threadIdx.x + k * 256;      // 0..8191
        const int r = idx >> 7, c = idx & 127;
        W2s[r][c] = W2e[(size_t)r * DIM + colbase + c];
    }

    for (int tile = blockIdx.z; tile * 64 < ne; tile += gridDim.z) {
        const int row0 = tile * 64;
        __syncthreads();   // W2s ready (1st iter) / previous tile done
        if (threadIdx.x < 64) {
            const int gr = row0 + threadIdx.x;
            tokS[threadIdx.x] = (gr < ne) ? token_list[n0 + gr] : -1;
        }
#pragma unroll
        for (int k = 0; k < 16; ++k) {
            const int idx = threadIdx.x + k * 256;
            const int r = idx >> 6, c = idx & 63;
            const int gr = row0 + r;
            PsT[c][r] = (gr < ne) ? P[(size_t)(n0 + gr) * RANK + c] : 0.f;
        }
        __syncthreads();
        float acc[4][8] = {};
#pragma unroll
        for (int k = 0; k < 64; ++k) {
            const float4 a  = *(const float4*)&PsT[k][ty * 4];
            const float4 b0 = *(const float4*)&W2s[k][tx * 4];
            const float4 b1 = *(const float4*)&W2s[k][64 + tx * 4];
            const float av[4] = {a.x, a.y, a.z, a.w};
            const float bv[8] = {b0.x, b0.y, b0.z, b0.w, b1.x, b1.y, b1.z, b1.w};
#pragma unroll
            for (int i = 0; i < 4; ++i)
#pragma unroll
                for (int j = 0; j < 8; ++j) acc[i][j] += av[i] * bv[j];
        }
#pragma unroll
        for (int i = 0; i < 4; ++i) {
            const int ent = tokS[ty * 4 + i];
            if (ent >= 0) {
                const int tok = ent >> 1;
                float* base = (ent & 1) ? contrib : out;
                float* op = base + (size_t)tok * DIM + colbase;
                float4 v0 = make_float4(acc[i][0], acc[i][1], acc[i][2], acc[i][3]);
                float4 v1 = make_float4(acc[i][4], acc[i][5], acc[i][6], acc[i][7]);
                *(float4*)(op + tx * 4) = v0;
                *(float4*)(op + 64 + tx * 4) = v1;
            }
        }
    }
}

// ---------------------------------------------------------------------------
// Combine: out += contrib (every token has exactly one j=0 and one j=1 slot,
// so both arrays are fully written).
// ---------------------------------------------------------------------------
__global__ __launch_bounds__(256) void combine_kernel(
    const float* __restrict__ contrib, float* __restrict__ out)
{
    const size_t i = (size_t)blockIdx.x * 256 + threadIdx.x;   // float4 index
    float4 a = ((const float4*)out)[i];
    const float4 b = ((const float4*)contrib)[i];
    a.x += b.x; a.y += b.y; a.z += b.z; a.w += b.w;
    ((float4*)out)[i] = a;
}

// ---------------------------------------------------------------------------
extern "C" void kernel_launch(void* const* d_in, const int* in_sizes, int n_in,
                              void* d_out, int out_size, void* d_ws, size_t ws_size,
                              hipStream_t stream)
{
    const float* h    = (const float*)d_in[0];
    const float* Wg   = (const float*)d_in[1];
    const float* bg   = (const float*)d_in[2];
    const float* Wloc = (const float*)d_in[3];
    const float* W1   = (const float*)d_in[4];
    const float* W2   = (const float*)d_in[5];
    // d_in[6] = k (constant 2 for this problem)

    float* out_f    = (float*)d_out;
    float* out_main = out_f;                               // (N, D)
    float* out_eid  = out_f + (size_t)NTOK * DIM;          // (N, 2) as floats
    float* out_gate = out_eid + (size_t)NTOK * 2;          // (N, 2)
    float* out_gidx = out_gate + (size_t)NTOK * 2;         // (N,)  as floats

    int* ws_i        = (int*)d_ws;
    int* counts      = ws_i;                 // 64
    int* offsets     = ws_i + 64;            // 65
    int* cursor      = ws_i + 192;           // 64
    int* ws_eids     = ws_i + 256;           // 16384
    int* token_list  = ws_i + 256 + 16384;   // 16384 (entry = tok*2 + j)
    float* ws_f      = (float*)(ws_i + 256 + 2 * 16384);
    float* ws_gates  = ws_f;                 // 16384
    float* slot_gate = ws_f + 16384;         // 16384
    float* P         = ws_f + 2 * 16384;     // 16384*64 floats = 4 MB
    float* contrib   = P + (size_t)16384 * RANK;  // NTOK*DIM floats = 32 MB

    hipMemsetAsync(counts, 0, 64 * sizeof(int), stream);
    // NOTE: no out memset needed — e2's j=0 stores fully initialize out_main.

    routing_kernel<<<NTOK / 4, 256, 0, stream>>>(h, Wg, bg, Wloc,
        out_eid, out_gate, out_gidx, ws_eids, ws_gates, counts);
    scan_kernel<<<1, 64, 0, stream>>>(counts, offsets, cursor);
    scatter_kernel<<<NTOK / 256, 256, 0, stream>>>(ws_eids, ws_gates, cursor,
        token_list, slot_gate);
    e1_kernel<<<dim3(NEXP, 8), 256, 0, stream>>>(h, W1, offsets, token_list,
        slot_gate, P);
    e2_kernel<<<dim3(NEXP, 8, 2), 256, 0, stream>>>(P, W2, offsets, token_list,
        out_main, contrib);
    combine_kernel<<<(NTOK * DIM / 4) / 256, 256, 0, stream>>>(contrib, out_main);
}

// Round 3
// 433.460 us; speedup vs baseline: 4.2670x; 3.1003x over previous
//
#include <hip/hip_runtime.h>
#include <cstdint>
#include <cstddef>

#define NTOK 8192
#define DIM  1024
#define NEXP 64
#define RANK 64
#define NGRP 8
#define NLOC 8

// ---------------------------------------------------------------------------
// Routing: one wave per token. fp32 exact (integer outputs must match np argmax).
// ---------------------------------------------------------------------------
__global__ __launch_bounds__(256) void routing_kernel(
    const float* __restrict__ h, const float* __restrict__ Wg,
    const float* __restrict__ bg, const float* __restrict__ Wloc,
    float* __restrict__ out_eid, float* __restrict__ out_gate,
    float* __restrict__ out_gidx,
    int* __restrict__ ws_eids, float* __restrict__ ws_gates,
    int* __restrict__ counts)
{
    const int wave = threadIdx.x >> 6;
    const int lane = threadIdx.x & 63;
    const int t = blockIdx.x * 4 + wave;

    const float* hrow = h + (size_t)t * DIM;
    float hreg[16];
#pragma unroll
    for (int i = 0; i < 16; ++i) hreg[i] = hrow[i * 64 + lane];

    // stage 1: group scores
    float acc[NGRP];
#pragma unroll
    for (int g = 0; g < NGRP; ++g) acc[g] = 0.f;
#pragma unroll
    for (int i = 0; i < 16; ++i) {
        const int d = i * 64 + lane;
        const float4* wp = (const float4*)(Wg + (size_t)d * NGRP);
        float4 w0 = wp[0], w1 = wp[1];
        const float hd = hreg[i];
        acc[0] += hd * w0.x; acc[1] += hd * w0.y;
        acc[2] += hd * w0.z; acc[3] += hd * w0.w;
        acc[4] += hd * w1.x; acc[5] += hd * w1.y;
        acc[6] += hd * w1.z; acc[7] += hd * w1.w;
    }
#pragma unroll
    for (int g = 0; g < NGRP; ++g) {
#pragma unroll
        for (int s = 32; s >= 1; s >>= 1) acc[g] += __shfl_xor(acc[g], s, 64);
        acc[g] += bg[g];
    }
    // argmax, first-index-wins (matches np/jnp argmax tie rule)
    int gi = 0; float best = acc[0];
#pragma unroll
    for (int g = 1; g < NGRP; ++g) { if (acc[g] > best) { best = acc[g]; gi = g; } }

    // stage 2: within-group scores for the selected group only
    float acc2[NLOC];
#pragma unroll
    for (int m = 0; m < NLOC; ++m) acc2[m] = 0.f;
    const float* wl = Wloc + (size_t)gi * DIM * NLOC;
#pragma unroll
    for (int i = 0; i < 16; ++i) {
        const int d = i * 64 + lane;
        const float4* wp = (const float4*)(wl + (size_t)d * NLOC);
        float4 w0 = wp[0], w1 = wp[1];
        const float hd = hreg[i];
        acc2[0] += hd * w0.x; acc2[1] += hd * w0.y;
        acc2[2] += hd * w0.z; acc2[3] += hd * w0.w;
        acc2[4] += hd * w1.x; acc2[5] += hd * w1.y;
        acc2[6] += hd * w1.z; acc2[7] += hd * w1.w;
    }
#pragma unroll
    for (int m = 0; m < NLOC; ++m) {
#pragma unroll
        for (int s = 32; s >= 1; s >>= 1) acc2[m] += __shfl_xor(acc2[m], s, 64);
    }
    // top-2, first-index-wins on ties (matches lax.top_k stability)
    int m1 = 0; float v1 = acc2[0];
#pragma unroll
    for (int m = 1; m < NLOC; ++m) { if (acc2[m] > v1) { v1 = acc2[m]; m1 = m; } }
    int m2 = (m1 == 0) ? 1 : 0; float v2 = acc2[m2];
#pragma unroll
    for (int m = 0; m < NLOC; ++m) {
        if (m != m1 && m != ((m1 == 0) ? 1 : 0) && acc2[m] > v2) { v2 = acc2[m]; m2 = m; }
    }
    // softmax over [v1, v2], v1 >= v2
    const float e2v = expf(v2 - v1);
    const float inv = 1.f / (1.f + e2v);
    const float g0 = inv, g1 = e2v * inv;
    const int e0 = gi * NLOC + m1, e1 = gi * NLOC + m2;

    if (lane == 0) {
        out_eid[t * 2 + 0] = (float)e0;
        out_eid[t * 2 + 1] = (float)e1;
        out_gate[t * 2 + 0] = g0;
        out_gate[t * 2 + 1] = g1;
        out_gidx[t] = (float)gi;
        ws_eids[t * 2 + 0] = e0;
        ws_eids[t * 2 + 1] = e1;
        ws_gates[t * 2 + 0] = g0;
        ws_gates[t * 2 + 1] = g1;
        atomicAdd(&counts[e0], 1);
        atomicAdd(&counts[e1], 1);
    }
}

// ---------------------------------------------------------------------------
// Exclusive scan over 64 expert counts (single wave).
// ---------------------------------------------------------------------------
__global__ __launch_bounds__(64) void scan_kernel(
    const int* __restrict__ counts, int* __restrict__ offsets, int* __restrict__ cursor)
{
    const int e = threadIdx.x;  // 0..63
    const int c = counts[e];
    int s = c;
#pragma unroll
    for (int d = 1; d < 64; d <<= 1) {
        int v = __shfl_up(s, d, 64);
        if (e >= d) s += v;
    }
    offsets[e] = s - c;
    cursor[e] = s - c;
    if (e == 63) offsets[64] = s;
}

// ---------------------------------------------------------------------------
// Scatter token ids into per-expert buckets. Entry encodes (token, slot-rank):
// entry = tok*2 + j, j in {0,1}. j=0 slots later write out directly (unique
// per token); j=1 slots write the contrib scratch. No output atomics anywhere.
// ---------------------------------------------------------------------------
__global__ __launch_bounds__(256) void scatter_kernel(
    const int* __restrict__ ws_eids, const float* __restrict__ ws_gates,
    int* __restrict__ cursor, int* __restrict__ token_list, float* __restrict__ slot_gate)
{
    const int t = blockIdx.x * 256 + threadIdx.x;
    if (t >= NTOK) return;
#pragma unroll
    for (int j = 0; j < 2; ++j) {
        const int eid = ws_eids[t * 2 + j];
        const int pos = atomicAdd(&cursor[eid], 1);
        token_list[pos] = t * 2 + j;
        slot_gate[pos] = ws_gates[t * 2 + j];
    }
}

// ---------------------------------------------------------------------------
// E1: P[slot, r] = gate * relu( h[tok] @ W1[e] ).  Tile 64 slots x 64 R,
// K-chunks of 64, 256 threads, 4x4 register blocking, float4 LDS reads.
// unroll 8 + launch_bounds(,2): keep VGPR use under the cap — full unroll
// hoisted all ds_reads, spilled to scratch, and turned the loop HBM-bound.
// ---------------------------------------------------------------------------
__global__ __launch_bounds__(256, 2) void e1_kernel(
    const float* __restrict__ h, const float* __restrict__ W1,
    const int* __restrict__ offsets, const int* __restrict__ token_list,
    const float* __restrict__ slot_gate, float* __restrict__ P)
{
    __shared__ float HsT[64][68];   // [k][slot]
    __shared__ float Ws[64][68];    // [k][r]
    __shared__ int   tokS[64];      // entry = tok*2+j, or -1 pad
    __shared__ float gateS[64];

    const int e = blockIdx.x;
    const int n0 = offsets[e];
    const int ne = offsets[e + 1] - n0;
    const float* W1e = W1 + (size_t)e * DIM * RANK;
    const int tx = threadIdx.x & 15, ty = threadIdx.x >> 4;

    for (int tile = blockIdx.y; tile * 64 < ne; tile += gridDim.y) {
        const int row0 = tile * 64;
        if (threadIdx.x < 64) {
            const int gr = row0 + threadIdx.x;
            tokS[threadIdx.x]  = (gr < ne) ? token_list[n0 + gr] : -1;
            gateS[threadIdx.x] = (gr < ne) ? slot_gate[n0 + gr] : 0.f;
        }
        float acc[4][4] = {};
        for (int kc = 0; kc < DIM; kc += 64) {
            __syncthreads();   // tokS ready (1st iter) / LDS reuse safe
#pragma unroll 8
            for (int k = 0; k < 16; ++k) {
                const int idx = threadIdx.x + k * 256;
                const int r = idx >> 6, c = idx & 63;
                const int ent = tokS[r];
                HsT[c][r] = (ent >= 0) ? h[(size_t)(ent >> 1) * DIM + kc + c] : 0.f;
                Ws[idx >> 6][idx & 63] = W1e[(size_t)kc * RANK + idx];
            }
            __syncthreads();
#pragma unroll 8
            for (int k = 0; k < 64; ++k) {
                const float4 a = *(const float4*)&HsT[k][ty * 4];
                const float4 b = *(const float4*)&Ws[k][tx * 4];
                const float av[4] = {a.x, a.y, a.z, a.w};
                const float bv[4] = {b.x, b.y, b.z, b.w};
#pragma unroll
                for (int i = 0; i < 4; ++i)
#pragma unroll
                    for (int j = 0; j < 4; ++j) acc[i][j] += av[i] * bv[j];
            }
        }
#pragma unroll
        for (int i = 0; i < 4; ++i) {
            const int gr = row0 + ty * 4 + i;
            if (gr < ne) {
                const float gt = gateS[ty * 4 + i];
                float4 v;
                v.x = fmaxf(acc[i][0], 0.f) * gt;
                v.y = fmaxf(acc[i][1], 0.f) * gt;
                v.z = fmaxf(acc[i][2], 0.f) * gt;
                v.w = fmaxf(acc[i][3], 0.f) * gt;
                *(float4*)&P[(size_t)(n0 + gr) * RANK + tx * 4] = v;
            }
        }
        __syncthreads();   // protect tokS/gateS before next tile overwrites
    }
}

// ---------------------------------------------------------------------------
// E2: C_slot = P[slot] @ W2[e].  Tile 64 slots x 128 cols, K=64 in one shot,
// 4x(4+4) register blocking. j=0 slots STORE to out[tok] (unique per token);
// j=1 slots STORE to contrib[tok]. Zero atomics. unroll 8 (see e1 note).
// ---------------------------------------------------------------------------
__global__ __launch_bounds__(256, 2) void e2_kernel(
    const float* __restrict__ P, const float* __restrict__ W2,
    const int* __restrict__ offsets, const int* __restrict__ token_list,
    float* __restrict__ out, float* __restrict__ contrib)
{
    __shared__ float PsT[64][68];    // [k][slot]
    __shared__ float W2s[64][132];   // [k][col 0..127]
    __shared__ int   tokS[64];

    const int e = blockIdx.x;
    const int colbase = blockIdx.y * 128;
    const int n0 = offsets[e];
    const int ne = offsets[e + 1] - n0;
    const float* W2e = W2 + (size_t)e * RANK * DIM;
    const int tx = threadIdx.x & 15, ty = threadIdx.x >> 4;

    // W2 tile: loaded once per block (K=64 total)
#pragma unroll 8
    for (int k = 0; k < 32; ++k) {
        const int idx = threadIdx.x + k * 256;      // 0..8191
        const int r = idx >> 7, c = idx & 127;
        W2s[r][c] = W2e[(size_t)r * DIM + colbase + c];
    }

    for (int tile = blockIdx.z; tile * 64 < ne; tile += gridDim.z) {
        const int row0 = tile * 64;
        __syncthreads();   // W2s ready (1st iter) / previous tile done
        if (threadIdx.x < 64) {
            const int gr = row0 + threadIdx.x;
            tokS[threadIdx.x] = (gr < ne) ? token_list[n0 + gr] : -1;
        }
#pragma unroll 8
        for (int k = 0; k < 16; ++k) {
            const int idx = threadIdx.x + k * 256;
            const int r = idx >> 6, c = idx & 63;
            const int gr = row0 + r;
            PsT[c][r] = (gr < ne) ? P[(size_t)(n0 + gr) * RANK + c] : 0.f;
        }
        __syncthreads();
        float acc[4][8] = {};
#pragma unroll 8
        for (int k = 0; k < 64; ++k) {
            const float4 a  = *(const float4*)&PsT[k][ty * 4];
            const float4 b0 = *(const float4*)&W2s[k][tx * 4];
            const float4 b1 = *(const float4*)&W2s[k][64 + tx * 4];
            const float av[4] = {a.x, a.y, a.z, a.w};
            const float bv[8] = {b0.x, b0.y, b0.z, b0.w, b1.x, b1.y, b1.z, b1.w};
#pragma unroll
            for (int i = 0; i < 4; ++i)
#pragma unroll
                for (int j = 0; j < 8; ++j) acc[i][j] += av[i] * bv[j];
        }
#pragma unroll
        for (int i = 0; i < 4; ++i) {
            const int ent = tokS[ty * 4 + i];
            if (ent >= 0) {
                const int tok = ent >> 1;
                float* base = (ent & 1) ? contrib : out;
                float* op = base + (size_t)tok * DIM + colbase;
                float4 v0 = make_float4(acc[i][0], acc[i][1], acc[i][2], acc[i][3]);
                float4 v1 = make_float4(acc[i][4], acc[i][5], acc[i][6], acc[i][7]);
                *(float4*)(op + tx * 4) = v0;
                *(float4*)(op + 64 + tx * 4) = v1;
            }
        }
    }
}

// ---------------------------------------------------------------------------
// Combine: out += contrib (every token has exactly one j=0 and one j=1 slot,
// so both arrays are fully written).
// ---------------------------------------------------------------------------
__global__ __launch_bounds__(256) void combine_kernel(
    const float* __restrict__ contrib, float* __restrict__ out)
{
    const size_t i = (size_t)blockIdx.x * 256 + threadIdx.x;   // float4 index
    float4 a = ((const float4*)out)[i];
    const float4 b = ((const float4*)contrib)[i];
    a.x += b.x; a.y += b.y; a.z += b.z; a.w += b.w;
    ((float4*)out)[i] = a;
}

// ---------------------------------------------------------------------------
extern "C" void kernel_launch(void* const* d_in, const int* in_sizes, int n_in,
                              void* d_out, int out_size, void* d_ws, size_t ws_size,
                              hipStream_t stream)
{
    const float* h    = (const float*)d_in[0];
    const float* Wg   = (const float*)d_in[1];
    const float* bg   = (const float*)d_in[2];
    const float* Wloc = (const float*)d_in[3];
    const float* W1   = (const float*)d_in[4];
    const float* W2   = (const float*)d_in[5];
    // d_in[6] = k (constant 2 for this problem)

    float* out_f    = (float*)d_out;
    float* out_main = out_f;                               // (N, D)
    float* out_eid  = out_f + (size_t)NTOK * DIM;          // (N, 2) as floats
    float* out_gate = out_eid + (size_t)NTOK * 2;          // (N, 2)
    float* out_gidx = out_gate + (size_t)NTOK * 2;         // (N,)  as floats

    int* ws_i        = (int*)d_ws;
    int* counts      = ws_i;                 // 64
    int* offsets     = ws_i + 64;            // 65
    int* cursor      = ws_i + 192;           // 64
    int* ws_eids     = ws_i + 256;           // 16384
    int* token_list  = ws_i + 256 + 16384;   // 16384 (entry = tok*2 + j)
    float* ws_f      = (float*)(ws_i + 256 + 2 * 16384);
    float* ws_gates  = ws_f;                 // 16384
    float* slot_gate = ws_f + 16384;         // 16384
    float* P         = ws_f + 2 * 16384;     // 16384*64 floats = 4 MB
    float* contrib   = P + (size_t)16384 * RANK;  // NTOK*DIM floats = 32 MB

    hipMemsetAsync(counts, 0, 64 * sizeof(int), stream);
    // NOTE: no out memset needed — e2's j=0 stores fully initialize out_main.

    routing_kernel<<<NTOK / 4, 256, 0, stream>>>(h, Wg, bg, Wloc,
        out_eid, out_gate, out_gidx, ws_eids, ws_gates, counts);
    scan_kernel<<<1, 64, 0, stream>>>(counts, offsets, cursor);
    scatter_kernel<<<NTOK / 256, 256, 0, stream>>>(ws_eids, ws_gates, cursor,
        token_list, slot_gate);
    e1_kernel<<<dim3(NEXP, 8), 256, 0, stream>>>(h, W1, offsets, token_list,
        slot_gate, P);
    e2_kernel<<<dim3(NEXP, 8, 2), 256, 0, stream>>>(P, W2, offsets, token_list,
        out_main, contrib);
    combine_kernel<<<(NTOK * DIM / 4) / 256, 256, 0, stream>>>(contrib, out_main);
}

// Round 4
// 372.163 us; speedup vs baseline: 4.9698x; 1.1647x over previous
//
#include <hip/hip_runtime.h>
#include <cstdint>
#include <cstddef>

#define NTOK 8192
#define DIM  1024
#define NEXP 64
#define RANK 64
#define NGRP 8
#define NLOC 8

// ---------------------------------------------------------------------------
// Routing: one wave per token. fp32 exact (integer outputs must match np argmax).
// ---------------------------------------------------------------------------
__global__ __launch_bounds__(256) void routing_kernel(
    const float* __restrict__ h, const float* __restrict__ Wg,
    const float* __restrict__ bg, const float* __restrict__ Wloc,
    float* __restrict__ out_eid, float* __restrict__ out_gate,
    float* __restrict__ out_gidx,
    int* __restrict__ ws_eids, float* __restrict__ ws_gates,
    int* __restrict__ counts)
{
    const int wave = threadIdx.x >> 6;
    const int lane = threadIdx.x & 63;
    const int t = blockIdx.x * 4 + wave;

    const float* hrow = h + (size_t)t * DIM;
    float hreg[16];
#pragma unroll
    for (int i = 0; i < 16; ++i) hreg[i] = hrow[i * 64 + lane];

    // stage 1: group scores
    float acc[NGRP];
#pragma unroll
    for (int g = 0; g < NGRP; ++g) acc[g] = 0.f;
#pragma unroll
    for (int i = 0; i < 16; ++i) {
        const int d = i * 64 + lane;
        const float4* wp = (const float4*)(Wg + (size_t)d * NGRP);
        float4 w0 = wp[0], w1 = wp[1];
        const float hd = hreg[i];
        acc[0] += hd * w0.x; acc[1] += hd * w0.y;
        acc[2] += hd * w0.z; acc[3] += hd * w0.w;
        acc[4] += hd * w1.x; acc[5] += hd * w1.y;
        acc[6] += hd * w1.z; acc[7] += hd * w1.w;
    }
#pragma unroll
    for (int g = 0; g < NGRP; ++g) {
#pragma unroll
        for (int s = 32; s >= 1; s >>= 1) acc[g] += __shfl_xor(acc[g], s, 64);
        acc[g] += bg[g];
    }
    // argmax, first-index-wins (matches np/jnp argmax tie rule)
    int gi = 0; float best = acc[0];
#pragma unroll
    for (int g = 1; g < NGRP; ++g) { if (acc[g] > best) { best = acc[g]; gi = g; } }

    // stage 2: within-group scores for the selected group only
    float acc2[NLOC];
#pragma unroll
    for (int m = 0; m < NLOC; ++m) acc2[m] = 0.f;
    const float* wl = Wloc + (size_t)gi * DIM * NLOC;
#pragma unroll
    for (int i = 0; i < 16; ++i) {
        const int d = i * 64 + lane;
        const float4* wp = (const float4*)(wl + (size_t)d * NLOC);
        float4 w0 = wp[0], w1 = wp[1];
        const float hd = hreg[i];
        acc2[0] += hd * w0.x; acc2[1] += hd * w0.y;
        acc2[2] += hd * w0.z; acc2[3] += hd * w0.w;
        acc2[4] += hd * w1.x; acc2[5] += hd * w1.y;
        acc2[6] += hd * w1.z; acc2[7] += hd * w1.w;
    }
#pragma unroll
    for (int m = 0; m < NLOC; ++m) {
#pragma unroll
        for (int s = 32; s >= 1; s >>= 1) acc2[m] += __shfl_xor(acc2[m], s, 64);
    }
    // top-2, first-index-wins on ties (matches lax.top_k stability)
    int m1 = 0; float v1 = acc2[0];
#pragma unroll
    for (int m = 1; m < NLOC; ++m) { if (acc2[m] > v1) { v1 = acc2[m]; m1 = m; } }
    int m2 = (m1 == 0) ? 1 : 0; float v2 = acc2[m2];
#pragma unroll
    for (int m = 0; m < NLOC; ++m) {
        if (m != m1 && m != ((m1 == 0) ? 1 : 0) && acc2[m] > v2) { v2 = acc2[m]; m2 = m; }
    }
    // softmax over [v1, v2], v1 >= v2
    const float e2v = expf(v2 - v1);
    const float inv = 1.f / (1.f + e2v);
    const float g0 = inv, g1 = e2v * inv;
    const int e0 = gi * NLOC + m1, e1 = gi * NLOC + m2;

    if (lane == 0) {
        out_eid[t * 2 + 0] = (float)e0;
        out_eid[t * 2 + 1] = (float)e1;
        out_gate[t * 2 + 0] = g0;
        out_gate[t * 2 + 1] = g1;
        out_gidx[t] = (float)gi;
        ws_eids[t * 2 + 0] = e0;
        ws_eids[t * 2 + 1] = e1;
        ws_gates[t * 2 + 0] = g0;
        ws_gates[t * 2 + 1] = g1;
        atomicAdd(&counts[e0], 1);
        atomicAdd(&counts[e1], 1);
    }
}

// ---------------------------------------------------------------------------
// Exclusive scan over 64 expert counts (single wave).
// ---------------------------------------------------------------------------
__global__ __launch_bounds__(64) void scan_kernel(
    const int* __restrict__ counts, int* __restrict__ offsets, int* __restrict__ cursor)
{
    const int e = threadIdx.x;  // 0..63
    const int c = counts[e];
    int s = c;
#pragma unroll
    for (int d = 1; d < 64; d <<= 1) {
        int v = __shfl_up(s, d, 64);
        if (e >= d) s += v;
    }
    offsets[e] = s - c;
    cursor[e] = s - c;
    if (e == 63) offsets[64] = s;
}

// ---------------------------------------------------------------------------
// Scatter token ids into per-expert buckets. Entry encodes (token, slot-rank):
// entry = tok*2 + j, j in {0,1}. j=0 slots later write out directly (unique
// per token); j=1 slots write the contrib scratch. No output atomics anywhere.
// ---------------------------------------------------------------------------
__global__ __launch_bounds__(256) void scatter_kernel(
    const int* __restrict__ ws_eids, const float* __restrict__ ws_gates,
    int* __restrict__ cursor, int* __restrict__ token_list, float* __restrict__ slot_gate)
{
    const int t = blockIdx.x * 256 + threadIdx.x;
    if (t >= NTOK) return;
#pragma unroll
    for (int j = 0; j < 2; ++j) {
        const int eid = ws_eids[t * 2 + j];
        const int pos = atomicAdd(&cursor[eid], 1);
        token_list[pos] = t * 2 + j;
        slot_gate[pos] = ws_gates[t * 2 + j];
    }
}

// ---------------------------------------------------------------------------
// E1: P[slot, r] = gate * relu( h[tok] @ W1[e] ).  Tile 32 slots x 64 R,
// K-chunks of 64, 256 threads, 2x4 register blocking.
// LDS layouts: Hs slot-major [slot][k] (stride-1 staging writes = conflict-
// free; A-reads are scalar broadcasts), Ws k-major [k][r] (b128 reads, 2-way
// = free; stride-1 staging writes). Grid (64,16) for ~520 active blocks.
// ---------------------------------------------------------------------------
__global__ __launch_bounds__(256, 2) void e1_kernel(
    const float* __restrict__ h, const float* __restrict__ W1,
    const int* __restrict__ offsets, const int* __restrict__ token_list,
    const float* __restrict__ slot_gate, float* __restrict__ P)
{
    __shared__ float Hs[32][65];    // [slot][k]  (pad 65: banks (s+k)%32)
    __shared__ float Ws[64][68];    // [k][r]     (pad 68: b128-aligned)
    __shared__ int   tokS[32];      // entry = tok*2+j, or -1 pad
    __shared__ float gateS[32];

    const int e = blockIdx.x;
    const int n0 = offsets[e];
    const int ne = offsets[e + 1] - n0;
    const float* W1e = W1 + (size_t)e * DIM * RANK;
    const int tx = threadIdx.x & 15, ty = threadIdx.x >> 4;

    for (int tile = blockIdx.y; tile * 32 < ne; tile += 16) {
        const int row0 = tile * 32;
        if (threadIdx.x < 32) {
            const int gr = row0 + threadIdx.x;
            tokS[threadIdx.x]  = (gr < ne) ? token_list[n0 + gr] : -1;
            gateS[threadIdx.x] = (gr < ne) ? slot_gate[n0 + gr] : 0.f;
        }
        float acc[2][4] = {};
        for (int kc = 0; kc < DIM; kc += 64) {
            __syncthreads();   // tokS ready (1st iter) / LDS reuse safe
            // Hs: 32 slots x 64 k = 2048 elems, 8 iters
#pragma unroll
            for (int it = 0; it < 8; ++it) {
                const int idx = threadIdx.x + it * 256;
                const int r = idx >> 6, c = idx & 63;
                const int ent = tokS[r];
                Hs[r][c] = (ent >= 0) ? h[(size_t)(ent >> 1) * DIM + kc + c] : 0.f;
            }
            // Ws: 64 k x 64 r = 4096 elems, 16 iters
#pragma unroll 8
            for (int it = 0; it < 16; ++it) {
                const int idx = threadIdx.x + it * 256;
                const int r = idx >> 6, c = idx & 63;
                Ws[r][c] = W1e[(size_t)(kc + r) * RANK + c];
            }
            __syncthreads();
#pragma unroll 8
            for (int k = 0; k < 64; ++k) {
                const float a0 = Hs[ty * 2 + 0][k];
                const float a1 = Hs[ty * 2 + 1][k];
                const float4 b = *(const float4*)&Ws[k][tx * 4];
                acc[0][0] += a0 * b.x; acc[0][1] += a0 * b.y;
                acc[0][2] += a0 * b.z; acc[0][3] += a0 * b.w;
                acc[1][0] += a1 * b.x; acc[1][1] += a1 * b.y;
                acc[1][2] += a1 * b.z; acc[1][3] += a1 * b.w;
            }
        }
#pragma unroll
        for (int i = 0; i < 2; ++i) {
            const int gr = row0 + ty * 2 + i;
            if (gr < ne) {
                const float gt = gateS[ty * 2 + i];
                float4 v;
                v.x = fmaxf(acc[i][0], 0.f) * gt;
                v.y = fmaxf(acc[i][1], 0.f) * gt;
                v.z = fmaxf(acc[i][2], 0.f) * gt;
                v.w = fmaxf(acc[i][3], 0.f) * gt;
                *(float4*)&P[(size_t)(n0 + gr) * RANK + tx * 4] = v;
            }
        }
        __syncthreads();   // protect tokS/gateS before next tile overwrites
    }
}

// ---------------------------------------------------------------------------
// E2: C_slot = P[slot] @ W2[e].  Tile 64 slots x 64 cols, K=64 in one shot,
// 4x4 register blocking. Ps slot-major (conflict-free staging), W2s k-major.
// j=0 slots STORE to out[tok]; j=1 slots STORE to contrib[tok]. Zero atomics.
// Grid (64, 16 col-chunks, 2) -> 2048 blocks, LDS 34 KB -> 4 blocks/CU.
// ---------------------------------------------------------------------------
__global__ __launch_bounds__(256, 2) void e2_kernel(
    const float* __restrict__ P, const float* __restrict__ W2,
    const int* __restrict__ offsets, const int* __restrict__ token_list,
    float* __restrict__ out, float* __restrict__ contrib)
{
    __shared__ float Ps[64][65];    // [slot][k]
    __shared__ float W2s[64][68];   // [k][col]
    __shared__ int   tokS[64];

    const int e = blockIdx.x;
    const int colbase = blockIdx.y * 64;
    const int n0 = offsets[e];
    const int ne = offsets[e + 1] - n0;
    const float* W2e = W2 + (size_t)e * RANK * DIM;
    const int tx = threadIdx.x & 15, ty = threadIdx.x >> 4;

    // W2 tile: 64 k x 64 cols, loaded once per block
#pragma unroll 8
    for (int it = 0; it < 16; ++it) {
        const int idx = threadIdx.x + it * 256;
        const int r = idx >> 6, c = idx & 63;
        W2s[r][c] = W2e[(size_t)r * DIM + colbase + c];
    }

    for (int tile = blockIdx.z; tile * 64 < ne; tile += 2) {
        const int row0 = tile * 64;
        __syncthreads();   // W2s ready (1st iter) / previous tile done
        if (threadIdx.x < 64) {
            const int gr = row0 + threadIdx.x;
            tokS[threadIdx.x] = (gr < ne) ? token_list[n0 + gr] : -1;
        }
        // Ps: 64 slots x 64 k, 16 iters, stride-1 writes
#pragma unroll 8
        for (int it = 0; it < 16; ++it) {
            const int idx = threadIdx.x + it * 256;
            const int r = idx >> 6, c = idx & 63;
            const int gr = row0 + r;
            Ps[r][c] = (gr < ne) ? P[(size_t)(n0 + gr) * RANK + c] : 0.f;
        }
        __syncthreads();
        float acc[4][4] = {};
#pragma unroll 8
        for (int k = 0; k < 64; ++k) {
            const float a0 = Ps[ty * 4 + 0][k];
            const float a1 = Ps[ty * 4 + 1][k];
            const float a2 = Ps[ty * 4 + 2][k];
            const float a3 = Ps[ty * 4 + 3][k];
            const float4 b = *(const float4*)&W2s[k][tx * 4];
            acc[0][0] += a0 * b.x; acc[0][1] += a0 * b.y; acc[0][2] += a0 * b.z; acc[0][3] += a0 * b.w;
            acc[1][0] += a1 * b.x; acc[1][1] += a1 * b.y; acc[1][2] += a1 * b.z; acc[1][3] += a1 * b.w;
            acc[2][0] += a2 * b.x; acc[2][1] += a2 * b.y; acc[2][2] += a2 * b.z; acc[2][3] += a2 * b.w;
            acc[3][0] += a3 * b.x; acc[3][1] += a3 * b.y; acc[3][2] += a3 * b.z; acc[3][3] += a3 * b.w;
        }
#pragma unroll
        for (int i = 0; i < 4; ++i) {
            const int ent = tokS[ty * 4 + i];
            if (ent >= 0) {
                const int tok = ent >> 1;
                float* base = (ent & 1) ? contrib : out;
                float* op = base + (size_t)tok * DIM + colbase;
                *(float4*)(op + tx * 4) =
                    make_float4(acc[i][0], acc[i][1], acc[i][2], acc[i][3]);
            }
        }
    }
}

// ---------------------------------------------------------------------------
// Combine: out += contrib (every token has exactly one j=0 and one j=1 slot,
// so both arrays are fully written).
// ---------------------------------------------------------------------------
__global__ __launch_bounds__(256) void combine_kernel(
    const float* __restrict__ contrib, float* __restrict__ out)
{
    const size_t i = (size_t)blockIdx.x * 256 + threadIdx.x;   // float4 index
    float4 a = ((const float4*)out)[i];
    const float4 b = ((const float4*)contrib)[i];
    a.x += b.x; a.y += b.y; a.z += b.z; a.w += b.w;
    ((float4*)out)[i] = a;
}

// ---------------------------------------------------------------------------
extern "C" void kernel_launch(void* const* d_in, const int* in_sizes, int n_in,
                              void* d_out, int out_size, void* d_ws, size_t ws_size,
                              hipStream_t stream)
{
    const float* h    = (const float*)d_in[0];
    const float* Wg   = (const float*)d_in[1];
    const float* bg   = (const float*)d_in[2];
    const float* Wloc = (const float*)d_in[3];
    const float* W1   = (const float*)d_in[4];
    const float* W2   = (const float*)d_in[5];
    // d_in[6] = k (constant 2 for this problem)

    float* out_f    = (float*)d_out;
    float* out_main = out_f;                               // (N, D)
    float* out_eid  = out_f + (size_t)NTOK * DIM;          // (N, 2) as floats
    float* out_gate = out_eid + (size_t)NTOK * 2;          // (N, 2)
    float* out_gidx = out_gate + (size_t)NTOK * 2;         // (N,)  as floats

    int* ws_i        = (int*)d_ws;
    int* counts      = ws_i;                 // 64
    int* offsets     = ws_i + 64;            // 65
    int* cursor      = ws_i + 192;           // 64
    int* ws_eids     = ws_i + 256;           // 16384
    int* token_list  = ws_i + 256 + 16384;   // 16384 (entry = tok*2 + j)
    float* ws_f      = (float*)(ws_i + 256 + 2 * 16384);
    float* ws_gates  = ws_f;                 // 16384
    float* slot_gate = ws_f + 16384;         // 16384
    float* P         = ws_f + 2 * 16384;     // 16384*64 floats = 4 MB
    float* contrib   = P + (size_t)16384 * RANK;  // NTOK*DIM floats = 32 MB

    hipMemsetAsync(counts, 0, 64 * sizeof(int), stream);
    // NOTE: no out memset needed — e2's j=0 stores fully initialize out_main.

    routing_kernel<<<NTOK / 4, 256, 0, stream>>>(h, Wg, bg, Wloc,
        out_eid, out_gate, out_gidx, ws_eids, ws_gates, counts);
    scan_kernel<<<1, 64, 0, stream>>>(counts, offsets, cursor);
    scatter_kernel<<<NTOK / 256, 256, 0, stream>>>(ws_eids, ws_gates, cursor,
        token_list, slot_gate);
    e1_kernel<<<dim3(NEXP, 16), 256, 0, stream>>>(h, W1, offsets, token_list,
        slot_gate, P);
    e2_kernel<<<dim3(NEXP, 16, 2), 256, 0, stream>>>(P, W2, offsets, token_list,
        out_main, contrib);
    combine_kernel<<<(NTOK * DIM / 4) / 256, 256, 0, stream>>>(contrib, out_main);
}

// Round 5
// 356.372 us; speedup vs baseline: 5.1901x; 1.0443x over previous
//
#include <hip/hip_runtime.h>
#include <cstdint>
#include <cstddef>

#define NTOK 8192
#define DIM  1024
#define NEXP 64
#define RANK 64
#define NGRP 8
#define NLOC 8

// ---------------------------------------------------------------------------
// Score GEMM: S[t][c] = sum_d h[t][d] * B[d][c], c in [0,72):
//   c in [0,64):  B[d][c] = Wloc[g=c>>3][d][m=c&7]   (local scores, all groups)
//   c in [64,72): B[d][c] = Wg[d][c-64]              (group scores)
// fp32 vector FMA (argmax outputs must match np fp32). 32 tokens/block,
// K-chunks of 64 staged in LDS. Output column-major: S_cm[c*NTOK + t]
// (coalesced consumption in route_kernel). Weights staged cooperatively —
// replaces the per-wave 64KB weight streams that thrashed L1 in the old
// routing kernel (VALUBusy 7%, latency-bound, 96 us).
// ---------------------------------------------------------------------------
__global__ __launch_bounds__(256, 2) void score_kernel(
    const float* __restrict__ h, const float* __restrict__ Wg,
    const float* __restrict__ Wloc, float* __restrict__ S_cm)
{
    __shared__ float Hs[32][65];   // [token][k]; pad 65 -> a-reads conflict-free
    __shared__ float Bs[64][80];   // [k][col]; row 320B (16B-aligned for b128)

    const int t0 = blockIdx.x * 32;
    const int tx = threadIdx.x & 15;   // token within half-tile
    const int ty = threadIdx.x >> 4;   // col group: float4 at ty*4, scalar 64+ty

    float acc[2][4] = {};   // 2 tokens x 4 local cols
    float accs[2] = {};     // 2 tokens x 1 group/pad col

    for (int kc = 0; kc < DIM; kc += 64) {
        __syncthreads();
        // Hs: 32 x 64 = 2048 elems, 8 iters, stride-1 writes
#pragma unroll
        for (int it = 0; it < 8; ++it) {
            const int idx = threadIdx.x + it * 256;
            const int r = idx >> 6, c = idx & 63;
            Hs[r][c] = h[(size_t)(t0 + r) * DIM + kc + c];
        }
        // Bs local cols: 64 x 64 = 4096 elems, 16 iters
#pragma unroll 8
        for (int it = 0; it < 16; ++it) {
            const int idx = threadIdx.x + it * 256;
            const int k = idx >> 6, c = idx & 63;
            Bs[k][c] = Wloc[(size_t)(c >> 3) * (DIM * NLOC) + (size_t)(kc + k) * NLOC + (c & 7)];
        }
        // Bs group cols 64..71: 64 x 8 = 512 elems, 2 iters
#pragma unroll
        for (int it = 0; it < 2; ++it) {
            const int idx = threadIdx.x + it * 256;
            const int k = idx >> 3, c8 = idx & 7;
            Bs[k][64 + c8] = Wg[(size_t)(kc + k) * NGRP + c8];
        }
        // Bs pad cols 72..79: zeros (read unconditionally, stored never)
#pragma unroll
        for (int it = 0; it < 2; ++it) {
            const int idx = threadIdx.x + it * 256;
            const int k = idx >> 3, c8 = idx & 7;
            Bs[k][72 + c8] = 0.f;
        }
        __syncthreads();
#pragma unroll 8
        for (int k = 0; k < 64; ++k) {
            const float a0 = Hs[tx][k];
            const float a1 = Hs[tx + 16][k];
            const float4 b = *(const float4*)&Bs[k][ty * 4];
            const float bs = Bs[k][64 + ty];
            acc[0][0] += a0 * b.x; acc[0][1] += a0 * b.y;
            acc[0][2] += a0 * b.z; acc[0][3] += a0 * b.w;
            acc[1][0] += a1 * b.x; acc[1][1] += a1 * b.y;
            acc[1][2] += a1 * b.z; acc[1][3] += a1 * b.w;
            accs[0] += a0 * bs;
            accs[1] += a1 * bs;
        }
    }
#pragma unroll
    for (int i = 0; i < 2; ++i) {
        const int t = t0 + tx + 16 * i;
#pragma unroll
        for (int j = 0; j < 4; ++j)
            S_cm[(size_t)(ty * 4 + j) * NTOK + t] = acc[i][j];
        if (ty < 8)
            S_cm[(size_t)(64 + ty) * NTOK + t] = accs[i];
    }
}

// ---------------------------------------------------------------------------
// Route: 1 thread/token. Coalesced column-major score reads, scalar
// argmax / top-2 / softmax with np first-index-wins tie rules.
// Counts via LDS histogram -> 64 global atomics per block.
// ---------------------------------------------------------------------------
__global__ __launch_bounds__(256) void route_kernel(
    const float* __restrict__ S_cm, const float* __restrict__ bg,
    float* __restrict__ out_eid, float* __restrict__ out_gate,
    float* __restrict__ out_gidx,
    int* __restrict__ ws_eids, float* __restrict__ ws_gates,
    int* __restrict__ counts)
{
    __shared__ int hist[NEXP];
    if (threadIdx.x < NEXP) hist[threadIdx.x] = 0;
    __syncthreads();

    const int t = blockIdx.x * 256 + threadIdx.x;

    // stage 1: group argmax (first-index-wins)
    float best = S_cm[(size_t)64 * NTOK + t] + bg[0];
    int gi = 0;
#pragma unroll
    for (int g = 1; g < NGRP; ++g) {
        const float v = S_cm[(size_t)(64 + g) * NTOK + t] + bg[g];
        if (v > best) { best = v; gi = g; }
    }
    // stage 2: top-2 of selected group's 8 local scores (first-index-wins)
    float ls[NLOC];
#pragma unroll
    for (int m = 0; m < NLOC; ++m) ls[m] = S_cm[(size_t)(gi * NLOC + m) * NTOK + t];
    int m1 = 0; float v1 = ls[0];
#pragma unroll
    for (int m = 1; m < NLOC; ++m) { if (ls[m] > v1) { v1 = ls[m]; m1 = m; } }
    int m2 = (m1 == 0) ? 1 : 0; float v2 = ls[m2];
#pragma unroll
    for (int m = 0; m < NLOC; ++m) {
        if (m != m1 && m != ((m1 == 0) ? 1 : 0) && ls[m] > v2) { v2 = ls[m]; m2 = m; }
    }
    const float e2v = expf(v2 - v1);
    const float inv = 1.f / (1.f + e2v);
    const float g0 = inv, g1 = e2v * inv;
    const int e0 = gi * NLOC + m1, e1 = gi * NLOC + m2;

    out_eid[t * 2 + 0] = (float)e0;
    out_eid[t * 2 + 1] = (float)e1;
    out_gate[t * 2 + 0] = g0;
    out_gate[t * 2 + 1] = g1;
    out_gidx[t] = (float)gi;
    ws_eids[t * 2 + 0] = e0;
    ws_eids[t * 2 + 1] = e1;
    ws_gates[t * 2 + 0] = g0;
    ws_gates[t * 2 + 1] = g1;
    atomicAdd(&hist[e0], 1);
    atomicAdd(&hist[e1], 1);

    __syncthreads();
    if (threadIdx.x < NEXP) atomicAdd(&counts[threadIdx.x], hist[threadIdx.x]);
}

// ---------------------------------------------------------------------------
// Exclusive scan over 64 expert counts (single wave).
// ---------------------------------------------------------------------------
__global__ __launch_bounds__(64) void scan_kernel(
    const int* __restrict__ counts, int* __restrict__ offsets, int* __restrict__ cursor)
{
    const int e = threadIdx.x;  // 0..63
    const int c = counts[e];
    int s = c;
#pragma unroll
    for (int d = 1; d < 64; d <<= 1) {
        int v = __shfl_up(s, d, 64);
        if (e >= d) s += v;
    }
    offsets[e] = s - c;
    cursor[e] = s - c;
    if (e == 63) offsets[64] = s;
}

// ---------------------------------------------------------------------------
// Scatter token ids into per-expert buckets. Entry encodes (token, slot-rank):
// entry = tok*2 + j, j in {0,1}. j=0 slots later write out directly (unique
// per token); j=1 slots write the contrib scratch. No output atomics anywhere.
// ---------------------------------------------------------------------------
__global__ __launch_bounds__(256) void scatter_kernel(
    const int* __restrict__ ws_eids, const float* __restrict__ ws_gates,
    int* __restrict__ cursor, int* __restrict__ token_list, float* __restrict__ slot_gate)
{
    const int t = blockIdx.x * 256 + threadIdx.x;
    if (t >= NTOK) return;
#pragma unroll
    for (int j = 0; j < 2; ++j) {
        const int eid = ws_eids[t * 2 + j];
        const int pos = atomicAdd(&cursor[eid], 1);
        token_list[pos] = t * 2 + j;
        slot_gate[pos] = ws_gates[t * 2 + j];
    }
}

// ---------------------------------------------------------------------------
// E1: P[slot, r] = gate * relu( h[tok] @ W1[e] ).  Tile 32 slots x 64 R,
// K-chunks of 64, 256 threads, 2x4 register blocking.
// LDS layouts: Hs slot-major [slot][k] (stride-1 staging writes = conflict-
// free; A-reads are scalar broadcasts), Ws k-major [k][r] (b128 reads, 2-way
// = free; stride-1 staging writes). Grid (64,16) for ~520 active blocks.
// ---------------------------------------------------------------------------
__global__ __launch_bounds__(256, 2) void e1_kernel(
    const float* __restrict__ h, const float* __restrict__ W1,
    const int* __restrict__ offsets, const int* __restrict__ token_list,
    const float* __restrict__ slot_gate, float* __restrict__ P)
{
    __shared__ float Hs[32][65];    // [slot][k]
    __shared__ float Ws[64][68];    // [k][r]
    __shared__ int   tokS[32];      // entry = tok*2+j, or -1 pad
    __shared__ float gateS[32];

    const int e = blockIdx.x;
    const int n0 = offsets[e];
    const int ne = offsets[e + 1] - n0;
    const float* W1e = W1 + (size_t)e * DIM * RANK;
    const int tx = threadIdx.x & 15, ty = threadIdx.x >> 4;

    for (int tile = blockIdx.y; tile * 32 < ne; tile += 16) {
        const int row0 = tile * 32;
        if (threadIdx.x < 32) {
            const int gr = row0 + threadIdx.x;
            tokS[threadIdx.x]  = (gr < ne) ? token_list[n0 + gr] : -1;
            gateS[threadIdx.x] = (gr < ne) ? slot_gate[n0 + gr] : 0.f;
        }
        float acc[2][4] = {};
        for (int kc = 0; kc < DIM; kc += 64) {
            __syncthreads();   // tokS ready (1st iter) / LDS reuse safe
#pragma unroll
            for (int it = 0; it < 8; ++it) {
                const int idx = threadIdx.x + it * 256;
                const int r = idx >> 6, c = idx & 63;
                const int ent = tokS[r];
                Hs[r][c] = (ent >= 0) ? h[(size_t)(ent >> 1) * DIM + kc + c] : 0.f;
            }
#pragma unroll 8
            for (int it = 0; it < 16; ++it) {
                const int idx = threadIdx.x + it * 256;
                const int r = idx >> 6, c = idx & 63;
                Ws[r][c] = W1e[(size_t)(kc + r) * RANK + c];
            }
            __syncthreads();
#pragma unroll 8
            for (int k = 0; k < 64; ++k) {
                const float a0 = Hs[ty * 2 + 0][k];
                const float a1 = Hs[ty * 2 + 1][k];
                const float4 b = *(const float4*)&Ws[k][tx * 4];
                acc[0][0] += a0 * b.x; acc[0][1] += a0 * b.y;
                acc[0][2] += a0 * b.z; acc[0][3] += a0 * b.w;
                acc[1][0] += a1 * b.x; acc[1][1] += a1 * b.y;
                acc[1][2] += a1 * b.z; acc[1][3] += a1 * b.w;
            }
        }
#pragma unroll
        for (int i = 0; i < 2; ++i) {
            const int gr = row0 + ty * 2 + i;
            if (gr < ne) {
                const float gt = gateS[ty * 2 + i];
                float4 v;
                v.x = fmaxf(acc[i][0], 0.f) * gt;
                v.y = fmaxf(acc[i][1], 0.f) * gt;
                v.z = fmaxf(acc[i][2], 0.f) * gt;
                v.w = fmaxf(acc[i][3], 0.f) * gt;
                *(float4*)&P[(size_t)(n0 + gr) * RANK + tx * 4] = v;
            }
        }
        __syncthreads();   // protect tokS/gateS before next tile overwrites
    }
}

// ---------------------------------------------------------------------------
// E2: C_slot = P[slot] @ W2[e].  Tile 64 slots x 64 cols, K=64 in one shot,
// 4x4 register blocking. Ps slot-major (conflict-free staging), W2s k-major.
// j=0 slots STORE to out[tok]; j=1 slots STORE to contrib[tok]. Zero atomics.
// Grid (64, 16 col-chunks, 2) -> 2048 blocks, LDS 34 KB -> 4 blocks/CU.
// ---------------------------------------------------------------------------
__global__ __launch_bounds__(256, 2) void e2_kernel(
    const float* __restrict__ P, const float* __restrict__ W2,
    const int* __restrict__ offsets, const int* __restrict__ token_list,
    float* __restrict__ out, float* __restrict__ contrib)
{
    __shared__ float Ps[64][65];    // [slot][k]
    __shared__ float W2s[64][68];   // [k][col]
    __shared__ int   tokS[64];

    const int e = blockIdx.x;
    const int colbase = blockIdx.y * 64;
    const int n0 = offsets[e];
    const int ne = offsets[e + 1] - n0;
    const float* W2e = W2 + (size_t)e * RANK * DIM;
    const int tx = threadIdx.x & 15, ty = threadIdx.x >> 4;

    // W2 tile: 64 k x 64 cols, loaded once per block
#pragma unroll 8
    for (int it = 0; it < 16; ++it) {
        const int idx = threadIdx.x + it * 256;
        const int r = idx >> 6, c = idx & 63;
        W2s[r][c] = W2e[(size_t)r * DIM + colbase + c];
    }

    for (int tile = blockIdx.z; tile * 64 < ne; tile += 2) {
        const int row0 = tile * 64;
        __syncthreads();   // W2s ready (1st iter) / previous tile done
        if (threadIdx.x < 64) {
            const int gr = row0 + threadIdx.x;
            tokS[threadIdx.x] = (gr < ne) ? token_list[n0 + gr] : -1;
        }
        // Ps: 64 slots x 64 k, 16 iters, stride-1 writes
#pragma unroll 8
        for (int it = 0; it < 16; ++it) {
            const int idx = threadIdx.x + it * 256;
            const int r = idx >> 6, c = idx & 63;
            const int gr = row0 + r;
            Ps[r][c] = (gr < ne) ? P[(size_t)(n0 + gr) * RANK + c] : 0.f;
        }
        __syncthreads();
        float acc[4][4] = {};
#pragma unroll 8
        for (int k = 0; k < 64; ++k) {
            const float a0 = Ps[ty * 4 + 0][k];
            const float a1 = Ps[ty * 4 + 1][k];
            const float a2 = Ps[ty * 4 + 2][k];
            const float a3 = Ps[ty * 4 + 3][k];
            const float4 b = *(const float4*)&W2s[k][tx * 4];
            acc[0][0] += a0 * b.x; acc[0][1] += a0 * b.y; acc[0][2] += a0 * b.z; acc[0][3] += a0 * b.w;
            acc[1][0] += a1 * b.x; acc[1][1] += a1 * b.y; acc[1][2] += a1 * b.z; acc[1][3] += a1 * b.w;
            acc[2][0] += a2 * b.x; acc[2][1] += a2 * b.y; acc[2][2] += a2 * b.z; acc[2][3] += a2 * b.w;
            acc[3][0] += a3 * b.x; acc[3][1] += a3 * b.y; acc[3][2] += a3 * b.z; acc[3][3] += a3 * b.w;
        }
#pragma unroll
        for (int i = 0; i < 4; ++i) {
            const int ent = tokS[ty * 4 + i];
            if (ent >= 0) {
                const int tok = ent >> 1;
                float* base = (ent & 1) ? contrib : out;
                float* op = base + (size_t)tok * DIM + colbase;
                *(float4*)(op + tx * 4) =
                    make_float4(acc[i][0], acc[i][1], acc[i][2], acc[i][3]);
            }
        }
    }
}

// ---------------------------------------------------------------------------
// Combine: out += contrib (every token has exactly one j=0 and one j=1 slot,
// so both arrays are fully written).
// ---------------------------------------------------------------------------
__global__ __launch_bounds__(256) void combine_kernel(
    const float* __restrict__ contrib, float* __restrict__ out)
{
    const size_t i = (size_t)blockIdx.x * 256 + threadIdx.x;   // float4 index
    float4 a = ((const float4*)out)[i];
    const float4 b = ((const float4*)contrib)[i];
    a.x += b.x; a.y += b.y; a.z += b.z; a.w += b.w;
    ((float4*)out)[i] = a;
}

// ---------------------------------------------------------------------------
extern "C" void kernel_launch(void* const* d_in, const int* in_sizes, int n_in,
                              void* d_out, int out_size, void* d_ws, size_t ws_size,
                              hipStream_t stream)
{
    const float* h    = (const float*)d_in[0];
    const float* Wg   = (const float*)d_in[1];
    const float* bg   = (const float*)d_in[2];
    const float* Wloc = (const float*)d_in[3];
    const float* W1   = (const float*)d_in[4];
    const float* W2   = (const float*)d_in[5];
    // d_in[6] = k (constant 2 for this problem)

    float* out_f    = (float*)d_out;
    float* out_main = out_f;                               // (N, D)
    float* out_eid  = out_f + (size_t)NTOK * DIM;          // (N, 2) as floats
    float* out_gate = out_eid + (size_t)NTOK * 2;          // (N, 2)
    float* out_gidx = out_gate + (size_t)NTOK * 2;         // (N,)  as floats

    int* ws_i        = (int*)d_ws;
    int* counts      = ws_i;                 // 64
    int* offsets     = ws_i + 64;            // 65
    int* cursor      = ws_i + 192;           // 64
    int* ws_eids     = ws_i + 256;           // 16384
    int* token_list  = ws_i + 256 + 16384;   // 16384 (entry = tok*2 + j)
    float* ws_f      = (float*)(ws_i + 256 + 2 * 16384);
    float* ws_gates  = ws_f;                 // 16384
    float* slot_gate = ws_f + 16384;         // 16384
    float* P         = ws_f + 2 * 16384;     // 16384*64 floats = 4 MB
    float* contrib   = P + (size_t)16384 * RANK;  // NTOK*DIM floats = 32 MB
    // S_cm (72*NTOK floats = 2.4 MB) ALIASES contrib: S_cm's lifetime
    // (score->route) ends before contrib's begins (e2->combine).
    float* S_cm      = contrib;

    hipMemsetAsync(counts, 0, 64 * sizeof(int), stream);
    // NOTE: no out memset needed — e2's j=0 stores fully initialize out_main.

    score_kernel<<<NTOK / 32, 256, 0, stream>>>(h, Wg, Wloc, S_cm);
    route_kernel<<<NTOK / 256, 256, 0, stream>>>(S_cm, bg,
        out_eid, out_gate, out_gidx, ws_eids, ws_gates, counts);
    scan_kernel<<<1, 64, 0, stream>>>(counts, offsets, cursor);
    scatter_kernel<<<NTOK / 256, 256, 0, stream>>>(ws_eids, ws_gates, cursor,
        token_list, slot_gate);
    e1_kernel<<<dim3(NEXP, 16), 256, 0, stream>>>(h, W1, offsets, token_list,
        slot_gate, P);
    e2_kernel<<<dim3(NEXP, 16, 2), 256, 0, stream>>>(P, W2, offsets, token_list,
        out_main, contrib);
    combine_kernel<<<(NTOK * DIM / 4) / 256, 256, 0, stream>>>(contrib, out_main);
}

// Round 6
// 273.318 us; speedup vs baseline: 6.7672x; 1.3039x over previous
//
#include <hip/hip_runtime.h>
#include <hip/hip_bf16.h>
#include <cstdint>
#include <cstddef>

#define NTOK 8192
#define DIM  1024
#define NEXP 64
#define RANK 64
#define NGRP 8
#define NLOC 8

typedef __attribute__((ext_vector_type(8))) short bf16x8;
typedef __attribute__((ext_vector_type(4))) float f32x4;

static __device__ inline unsigned int pack_bf16x2(float a, float b) {
    __hip_bfloat16 ha = __float2bfloat16(a);
    __hip_bfloat16 hb = __float2bfloat16(b);
    return (unsigned int)(*(unsigned short*)&ha) |
           ((unsigned int)(*(unsigned short*)&hb) << 16);
}

// ---------------------------------------------------------------------------
// Score GEMM (fp32 — argmax/int outputs must match np fp32 exactly).
// S[t][c], c in [0,72): local scores (64) then group scores (8).
// Output column-major S_cm[c*NTOK + t].
// ---------------------------------------------------------------------------
__global__ __launch_bounds__(256, 2) void score_kernel(
    const float* __restrict__ h, const float* __restrict__ Wg,
    const float* __restrict__ Wloc, float* __restrict__ S_cm)
{
    __shared__ float Hs[32][65];
    __shared__ float Bs[64][80];

    const int t0 = blockIdx.x * 32;
    const int tx = threadIdx.x & 15;
    const int ty = threadIdx.x >> 4;

    float acc[2][4] = {};
    float accs[2] = {};

    for (int kc = 0; kc < DIM; kc += 64) {
        __syncthreads();
#pragma unroll
        for (int it = 0; it < 8; ++it) {
            const int idx = threadIdx.x + it * 256;
            const int r = idx >> 6, c = idx & 63;
            Hs[r][c] = h[(size_t)(t0 + r) * DIM + kc + c];
        }
#pragma unroll 8
        for (int it = 0; it < 16; ++it) {
            const int idx = threadIdx.x + it * 256;
            const int k = idx >> 6, c = idx & 63;
            Bs[k][c] = Wloc[(size_t)(c >> 3) * (DIM * NLOC) + (size_t)(kc + k) * NLOC + (c & 7)];
        }
#pragma unroll
        for (int it = 0; it < 2; ++it) {
            const int idx = threadIdx.x + it * 256;
            const int k = idx >> 3, c8 = idx & 7;
            Bs[k][64 + c8] = Wg[(size_t)(kc + k) * NGRP + c8];
            Bs[k][72 + c8] = 0.f;
        }
        __syncthreads();
#pragma unroll 8
        for (int k = 0; k < 64; ++k) {
            const float a0 = Hs[tx][k];
            const float a1 = Hs[tx + 16][k];
            const float4 b = *(const float4*)&Bs[k][ty * 4];
            const float bs = Bs[k][64 + ty];
            acc[0][0] += a0 * b.x; acc[0][1] += a0 * b.y;
            acc[0][2] += a0 * b.z; acc[0][3] += a0 * b.w;
            acc[1][0] += a1 * b.x; acc[1][1] += a1 * b.y;
            acc[1][2] += a1 * b.z; acc[1][3] += a1 * b.w;
            accs[0] += a0 * bs;
            accs[1] += a1 * bs;
        }
    }
#pragma unroll
    for (int i = 0; i < 2; ++i) {
        const int t = t0 + tx + 16 * i;
#pragma unroll
        for (int j = 0; j < 4; ++j)
            S_cm[(size_t)(ty * 4 + j) * NTOK + t] = acc[i][j];
        if (ty < 8)
            S_cm[(size_t)(64 + ty) * NTOK + t] = accs[i];
    }
}

// ---------------------------------------------------------------------------
// Route: 1 thread/token, np first-index-wins tie rules. fp32 exact.
// ---------------------------------------------------------------------------
__global__ __launch_bounds__(256) void route_kernel(
    const float* __restrict__ S_cm, const float* __restrict__ bg,
    float* __restrict__ out_eid, float* __restrict__ out_gate,
    float* __restrict__ out_gidx,
    int* __restrict__ ws_eids, float* __restrict__ ws_gates,
    int* __restrict__ counts)
{
    __shared__ int hist[NEXP];
    if (threadIdx.x < NEXP) hist[threadIdx.x] = 0;
    __syncthreads();

    const int t = blockIdx.x * 256 + threadIdx.x;

    float best = S_cm[(size_t)64 * NTOK + t] + bg[0];
    int gi = 0;
#pragma unroll
    for (int g = 1; g < NGRP; ++g) {
        const float v = S_cm[(size_t)(64 + g) * NTOK + t] + bg[g];
        if (v > best) { best = v; gi = g; }
    }
    float ls[NLOC];
#pragma unroll
    for (int m = 0; m < NLOC; ++m) ls[m] = S_cm[(size_t)(gi * NLOC + m) * NTOK + t];
    int m1 = 0; float v1 = ls[0];
#pragma unroll
    for (int m = 1; m < NLOC; ++m) { if (ls[m] > v1) { v1 = ls[m]; m1 = m; } }
    int m2 = (m1 == 0) ? 1 : 0; float v2 = ls[m2];
#pragma unroll
    for (int m = 0; m < NLOC; ++m) {
        if (m != m1 && m != ((m1 == 0) ? 1 : 0) && ls[m] > v2) { v2 = ls[m]; m2 = m; }
    }
    const float e2v = expf(v2 - v1);
    const float inv = 1.f / (1.f + e2v);
    const float g0 = inv, g1 = e2v * inv;
    const int e0 = gi * NLOC + m1, e1 = gi * NLOC + m2;

    out_eid[t * 2 + 0] = (float)e0;
    out_eid[t * 2 + 1] = (float)e1;
    out_gate[t * 2 + 0] = g0;
    out_gate[t * 2 + 1] = g1;
    out_gidx[t] = (float)gi;
    ws_eids[t * 2 + 0] = e0;
    ws_eids[t * 2 + 1] = e1;
    ws_gates[t * 2 + 0] = g0;
    ws_gates[t * 2 + 1] = g1;
    atomicAdd(&hist[e0], 1);
    atomicAdd(&hist[e1], 1);

    __syncthreads();
    if (threadIdx.x < NEXP) atomicAdd(&counts[threadIdx.x], hist[threadIdx.x]);
}

// ---------------------------------------------------------------------------
__global__ __launch_bounds__(64) void scan_kernel(
    const int* __restrict__ counts, int* __restrict__ offsets, int* __restrict__ cursor)
{
    const int e = threadIdx.x;
    const int c = counts[e];
    int s = c;
#pragma unroll
    for (int d = 1; d < 64; d <<= 1) {
        int v = __shfl_up(s, d, 64);
        if (e >= d) s += v;
    }
    offsets[e] = s - c;
    cursor[e] = s - c;
    if (e == 63) offsets[64] = s;
}

// ---------------------------------------------------------------------------
__global__ __launch_bounds__(256) void scatter_kernel(
    const int* __restrict__ ws_eids, const float* __restrict__ ws_gates,
    int* __restrict__ cursor, int* __restrict__ token_list, float* __restrict__ slot_gate)
{
    const int t = blockIdx.x * 256 + threadIdx.x;
    if (t >= NTOK) return;
#pragma unroll
    for (int j = 0; j < 2; ++j) {
        const int eid = ws_eids[t * 2 + j];
        const int pos = atomicAdd(&cursor[eid], 1);
        token_list[pos] = t * 2 + j;
        slot_gate[pos] = ws_gates[t * 2 + j];
    }
}

// ---------------------------------------------------------------------------
// cast_h: h fp32 -> hb bf16 (row layout unchanged). 8 elems/thread.
// ---------------------------------------------------------------------------
__global__ __launch_bounds__(256) void cast_h(
    const float* __restrict__ h, unsigned short* __restrict__ hb)
{
    const size_t i0 = ((size_t)blockIdx.x * 256 + threadIdx.x) * 8;
    const float4 x = *(const float4*)(h + i0);
    const float4 y = *(const float4*)(h + i0 + 4);
    uint4 v;
    v.x = pack_bf16x2(x.x, x.y);
    v.y = pack_bf16x2(x.z, x.w);
    v.z = pack_bf16x2(y.x, y.y);
    v.w = pack_bf16x2(y.z, y.w);
    *(uint4*)(hb + i0) = v;
}

// ---------------------------------------------------------------------------
// prep_w1: W1 fp32 [e][k=1024][r=64] -> W1t bf16 [e][r][k=1024]
// (MFMA B-operand needs k-contiguous per column). 64x64 LDS transpose tiles.
// ---------------------------------------------------------------------------
__global__ __launch_bounds__(256) void prep_w1(
    const float* __restrict__ W1, unsigned short* __restrict__ W1t)
{
    __shared__ float Ls[64][65];
    const int e = blockIdx.x, kb = blockIdx.y;   // kb in [0,16)
    const float* src = W1 + (size_t)e * DIM * RANK + (size_t)kb * 64 * RANK;
#pragma unroll
    for (int it = 0; it < 4; ++it) {
        const int kk = (threadIdx.x >> 4) + it * 16;
        const int rr = (threadIdx.x & 15) * 4;
        *(float4*)&Ls[kk][rr] = *(const float4*)(src + (size_t)kk * RANK + rr);
    }
    __syncthreads();
#pragma unroll
    for (int it = 0; it < 2; ++it) {
        const int idx = threadIdx.x + it * 256;
        const int r = idx >> 3, k8 = (idx & 7) * 8;
        uint4 v;
        v.x = pack_bf16x2(Ls[k8 + 0][r], Ls[k8 + 1][r]);
        v.y = pack_bf16x2(Ls[k8 + 2][r], Ls[k8 + 3][r]);
        v.z = pack_bf16x2(Ls[k8 + 4][r], Ls[k8 + 5][r]);
        v.w = pack_bf16x2(Ls[k8 + 6][r], Ls[k8 + 7][r]);
        *(uint4*)(W1t + (size_t)e * RANK * DIM + (size_t)r * DIM + kb * 64 + k8) = v;
    }
}

// ---------------------------------------------------------------------------
// prep_w2: W2 fp32 [e][r=64][d=1024] -> W2t bf16 [e][d][r=64]
// ---------------------------------------------------------------------------
__global__ __launch_bounds__(256) void prep_w2(
    const float* __restrict__ W2, unsigned short* __restrict__ W2t)
{
    __shared__ float Ls[64][65];
    const int e = blockIdx.x, db = blockIdx.y;   // db in [0,16)
    const float* src = W2 + (size_t)e * RANK * DIM + db * 64;
#pragma unroll
    for (int it = 0; it < 4; ++it) {
        const int rr = (threadIdx.x >> 4) + it * 16;
        const int dd = (threadIdx.x & 15) * 4;
        *(float4*)&Ls[rr][dd] = *(const float4*)(src + (size_t)rr * DIM + dd);
    }
    __syncthreads();
#pragma unroll
    for (int it = 0; it < 2; ++it) {
        const int idx = threadIdx.x + it * 256;
        const int d = idx >> 3, r8 = (idx & 7) * 8;
        uint4 v;
        v.x = pack_bf16x2(Ls[r8 + 0][d], Ls[r8 + 1][d]);
        v.y = pack_bf16x2(Ls[r8 + 2][d], Ls[r8 + 3][d]);
        v.z = pack_bf16x2(Ls[r8 + 4][d], Ls[r8 + 5][d]);
        v.w = pack_bf16x2(Ls[r8 + 6][d], Ls[r8 + 7][d]);
        *(uint4*)(W2t + (size_t)e * DIM * RANK + (size_t)(db * 64 + d) * RANK + r8) = v;
    }
}

// ---------------------------------------------------------------------------
// E1 (MFMA): P[slot][r] = bf16( gate * relu(h[tok] @ W1[e]) ).
// Block = 4 waves, tile 64 slots x 64 R; wave w owns slots [16w,16w+16) x all R.
// K=1024 in chunks of 64 (2 MFMA K-steps each). Fragments per m89-verified
// mapping: a=A[m=lane&15][k=quad*8+j], b=Bt[n=lane&15][k], D[m=quad*4+reg][n=lane&15].
// ---------------------------------------------------------------------------
__global__ __launch_bounds__(256, 2) void e1_mfma(
    const unsigned short* __restrict__ hb, const unsigned short* __restrict__ W1t,
    const int* __restrict__ offsets, const int* __restrict__ token_list,
    const float* __restrict__ slot_gate, unsigned short* __restrict__ P)
{
    __shared__ unsigned short Hs[64 * 72];   // [slot][k], rows 144B (16B-aligned)
    __shared__ unsigned short Ws[64 * 72];   // [r][k]
    __shared__ int   tokS[64];
    __shared__ float gateS[64];

    const int e  = blockIdx.x;
    const int n0 = offsets[e];
    const int ne = offsets[e + 1] - n0;
    const unsigned short* W1te = W1t + (size_t)e * RANK * DIM;
    const int tid  = threadIdx.x;
    const int wave = tid >> 6;
    const int lane = tid & 63;
    const int tx   = lane & 15;
    const int quad = lane >> 4;

    for (int tile = blockIdx.y; tile * 64 < ne; tile += 8) {
        const int row0 = tile * 64;
        __syncthreads();   // protect prev tile's tokS/gateS/LDS reads
        if (tid < 64) {
            const int gr = row0 + tid;
            tokS[tid]  = (gr < ne) ? token_list[n0 + gr] : -1;
            gateS[tid] = (gr < ne) ? slot_gate[n0 + gr] : 0.f;
        }
        f32x4 acc[4] = {};
        for (int kc = 0; kc < DIM; kc += 64) {
            __syncthreads();   // tokS ready (1st) / prev chunk's reads done
#pragma unroll
            for (int it = 0; it < 2; ++it) {
                const int idx = tid + it * 256;
                const int s = idx >> 3, k8 = (idx & 7) * 8;
                const int ent = tokS[s];
                uint4 v = make_uint4(0, 0, 0, 0);
                if (ent >= 0)
                    v = *(const uint4*)(hb + (size_t)(ent >> 1) * DIM + kc + k8);
                *(uint4*)(Hs + s * 72 + k8) = v;
            }
#pragma unroll
            for (int it = 0; it < 2; ++it) {
                const int idx = tid + it * 256;
                const int r = idx >> 3, k8 = (idx & 7) * 8;
                *(uint4*)(Ws + r * 72 + k8) =
                    *(const uint4*)(W1te + (size_t)r * DIM + kc + k8);
            }
            __syncthreads();
#pragma unroll
            for (int ks = 0; ks < 2; ++ks) {
                const bf16x8 a = *(const bf16x8*)(Hs + (wave * 16 + tx) * 72 + ks * 32 + quad * 8);
#pragma unroll
                for (int j = 0; j < 4; ++j) {
                    const bf16x8 b = *(const bf16x8*)(Ws + (j * 16 + tx) * 72 + ks * 32 + quad * 8);
                    acc[j] = __builtin_amdgcn_mfma_f32_16x16x32_bf16(a, b, acc[j], 0, 0, 0);
                }
            }
        }
        // epilogue: relu * gate, cast bf16, store P[slot][r]
#pragma unroll
        for (int j = 0; j < 4; ++j) {
#pragma unroll
            for (int i = 0; i < 4; ++i) {
                const int sl = wave * 16 + quad * 4 + i;
                const int gr = row0 + sl;
                if (gr < ne) {
                    const float v = fmaxf(acc[j][i], 0.f) * gateS[sl];
                    __hip_bfloat16 hv = __float2bfloat16(v);
                    P[(size_t)(n0 + gr) * RANK + j * 16 + tx] = *(unsigned short*)&hv;
                }
            }
        }
    }
}

// ---------------------------------------------------------------------------
// E2 (MFMA): C = P[slot] @ W2[e], K=RANK=64 (2 K-steps, no k-loop).
// Tile 64 slots x 64 cols; j=0 slots store out[tok], j=1 store contrib[tok].
// ---------------------------------------------------------------------------
__global__ __launch_bounds__(256, 2) void e2_mfma(
    const unsigned short* __restrict__ P, const unsigned short* __restrict__ W2t,
    const int* __restrict__ offsets, const int* __restrict__ token_list,
    float* __restrict__ out, float* __restrict__ contrib)
{
    __shared__ unsigned short Ps[64 * 72];    // [slot][r]
    __shared__ unsigned short W2s[64 * 72];   // [d][r]
    __shared__ int tokS[64];

    const int e = blockIdx.x;
    const int colbase = blockIdx.y * 64;
    const int n0 = offsets[e];
    const int ne = offsets[e + 1] - n0;
    const unsigned short* W2te = W2t + (size_t)e * DIM * RANK;
    const int tid  = threadIdx.x;
    const int wave = tid >> 6;
    const int lane = tid & 63;
    const int tx   = lane & 15;
    const int quad = lane >> 4;

    // stage W2s once per block: 64 d x 64 r
#pragma unroll
    for (int it = 0; it < 2; ++it) {
        const int idx = tid + it * 256;
        const int d = idx >> 3, r8 = (idx & 7) * 8;
        *(uint4*)(W2s + d * 72 + r8) =
            *(const uint4*)(W2te + (size_t)(colbase + d) * RANK + r8);
    }

    for (int tile = blockIdx.z; tile * 64 < ne; tile += 4) {
        const int row0 = tile * 64;
        __syncthreads();   // W2s ready (1st) / prev tile's reads done
        if (tid < 64) {
            const int gr = row0 + tid;
            tokS[tid] = (gr < ne) ? token_list[n0 + gr] : -1;
        }
#pragma unroll
        for (int it = 0; it < 2; ++it) {
            const int idx = tid + it * 256;
            const int s = idx >> 3, r8 = (idx & 7) * 8;
            const int gr = row0 + s;
            uint4 v = make_uint4(0, 0, 0, 0);
            if (gr < ne) v = *(const uint4*)(P + (size_t)(n0 + gr) * RANK + r8);
            *(uint4*)(Ps + s * 72 + r8) = v;
        }
        __syncthreads();
        f32x4 acc[4] = {};
#pragma unroll
        for (int ks = 0; ks < 2; ++ks) {
            const bf16x8 a = *(const bf16x8*)(Ps + (wave * 16 + tx) * 72 + ks * 32 + quad * 8);
#pragma unroll
            for (int j = 0; j < 4; ++j) {
                const bf16x8 b = *(const bf16x8*)(W2s + (j * 16 + tx) * 72 + ks * 32 + quad * 8);
                acc[j] = __builtin_amdgcn_mfma_f32_16x16x32_bf16(a, b, acc[j], 0, 0, 0);
            }
        }
#pragma unroll
        for (int i = 0; i < 4; ++i) {
            const int sl = wave * 16 + quad * 4 + i;
            const int ent = tokS[sl];
            if (ent >= 0) {
                float* base = (ent & 1) ? contrib : out;
                float* op = base + (size_t)(ent >> 1) * DIM + colbase;
#pragma unroll
                for (int j = 0; j < 4; ++j)
                    op[j * 16 + tx] = acc[j][i];
            }
        }
    }
}

// ---------------------------------------------------------------------------
__global__ __launch_bounds__(256) void combine_kernel(
    const float* __restrict__ contrib, float* __restrict__ out)
{
    const size_t i = (size_t)blockIdx.x * 256 + threadIdx.x;
    float4 a = ((const float4*)out)[i];
    const float4 b = ((const float4*)contrib)[i];
    a.x += b.x; a.y += b.y; a.z += b.z; a.w += b.w;
    ((float4*)out)[i] = a;
}

// ---------------------------------------------------------------------------
extern "C" void kernel_launch(void* const* d_in, const int* in_sizes, int n_in,
                              void* d_out, int out_size, void* d_ws, size_t ws_size,
                              hipStream_t stream)
{
    const float* h    = (const float*)d_in[0];
    const float* Wg   = (const float*)d_in[1];
    const float* bg   = (const float*)d_in[2];
    const float* Wloc = (const float*)d_in[3];
    const float* W1   = (const float*)d_in[4];
    const float* W2   = (const float*)d_in[5];

    float* out_f    = (float*)d_out;
    float* out_main = out_f;
    float* out_eid  = out_f + (size_t)NTOK * DIM;
    float* out_gate = out_eid + (size_t)NTOK * 2;
    float* out_gidx = out_gate + (size_t)NTOK * 2;

    int* ws_i        = (int*)d_ws;
    int* counts      = ws_i;                  // 64
    int* offsets     = ws_i + 64;             // 65
    int* cursor      = ws_i + 192;            // 64
    int* ws_eids     = ws_i + 256;            // 16384
    int* token_list  = ws_i + 256 + 16384;    // 16384 (entry = tok*2 + j)
    float* ws_f      = (float*)(ws_i + 256 + 2 * 16384);
    float* ws_gates  = ws_f;                  // 16384
    float* slot_gate = ws_f + 16384;          // 16384
    unsigned short* P_h  = (unsigned short*)(ws_f + 2 * 16384);        // 16384*64 bf16 = 2 MB
    unsigned short* W1t  = P_h + (size_t)16384 * RANK;                 // 4M bf16 = 8 MB
    unsigned short* W2t  = W1t + (size_t)NEXP * RANK * DIM;            // 4M bf16 = 8 MB
    float* contrib       = (float*)(W2t + (size_t)NEXP * DIM * RANK);  // 32 MB
    // Aliases inside the contrib region (lifetimes are disjoint, stream-serial):
    //   S_cm (2.4 MB): live score->route.
    //   hb  (16.8 MB): written by cast_h AFTER route, read by e1, then
    //                  clobbered by e2's contrib stores (e1 already done).
    float* S_cm = contrib;
    unsigned short* hb = (unsigned short*)contrib;

    hipMemsetAsync(counts, 0, 64 * sizeof(int), stream);

    prep_w1<<<dim3(NEXP, 16), 256, 0, stream>>>(W1, W1t);
    prep_w2<<<dim3(NEXP, 16), 256, 0, stream>>>(W2, W2t);
    score_kernel<<<NTOK / 32, 256, 0, stream>>>(h, Wg, Wloc, S_cm);
    route_kernel<<<NTOK / 256, 256, 0, stream>>>(S_cm, bg,
        out_eid, out_gate, out_gidx, ws_eids, ws_gates, counts);
    scan_kernel<<<1, 64, 0, stream>>>(counts, offsets, cursor);
    scatter_kernel<<<NTOK / 256, 256, 0, stream>>>(ws_eids, ws_gates, cursor,
        token_list, slot_gate);
    cast_h<<<(NTOK * DIM / 8) / 256, 256, 0, stream>>>(h, hb);
    e1_mfma<<<dim3(NEXP, 8), 256, 0, stream>>>(hb, W1t, offsets, token_list,
        slot_gate, P_h);
    e2_mfma<<<dim3(NEXP, 16, 4), 256, 0, stream>>>(P_h, W2t, offsets, token_list,
        out_main, contrib);
    combine_kernel<<<(NTOK * DIM / 4) / 256, 256, 0, stream>>>(contrib, out_main);
}

// Round 7
// 272.812 us; speedup vs baseline: 6.7797x; 1.0019x over previous
//
#include <hip/hip_runtime.h>
#include <hip/hip_bf16.h>
#include <cstdint>
#include <cstddef>

#define NTOK 8192
#define DIM  1024
#define NEXP 64
#define RANK 64
#define NGRP 8
#define NLOC 8

typedef __attribute__((ext_vector_type(8))) short bf16x8;
typedef __attribute__((ext_vector_type(4))) float f32x4;

static __device__ inline unsigned int pack_bf16x2(float a, float b) {
    __hip_bfloat16 ha = __float2bfloat16(a);
    __hip_bfloat16 hb = __float2bfloat16(b);
    return (unsigned int)(*(unsigned short*)&ha) |
           ((unsigned int)(*(unsigned short*)&hb) << 16);
}

// ---------------------------------------------------------------------------
// Stage 1: group scores (8192 x 8 x 1024, fp32-exact for argmax) FUSED with
// h -> bf16 cast (h is staged through LDS anyway; saves a 33.5 MB pass).
// 16 tokens/block, 512 blocks. Thread (t = tid&15, kq = tid>>4): kq covers
// k = (kq>>2)*16 + kk*4 + (kq&3), kk<4 — within a wave the 4 k's per iter are
// CONSECUTIVE so Bs b128 broadcasts hit distinct banks; Hs pad 66 makes
// a-reads 2-way (free). Per-(t,kq) partials reduced via LDS, then argmax.
// ---------------------------------------------------------------------------
__global__ __launch_bounds__(256, 4) void score_g_cast(
    const float* __restrict__ h, const float* __restrict__ Wg,
    const float* __restrict__ bg, unsigned short* __restrict__ hb,
    float* __restrict__ out_gidx, int* __restrict__ gidx_i,
    int* __restrict__ counts_g)
{
    __shared__ float Hs[16][66];
    __shared__ float Bs[64 * 8];
    __shared__ float Sp[16][16][8];   // [t][kq][m]
    __shared__ float Sg[16][9];
    __shared__ int   hist_g[NGRP];

    const int t0  = blockIdx.x * 16;
    const int tid = threadIdx.x;
    const int t   = tid & 15;
    const int kq  = tid >> 4;
    const int kbase = (kq >> 2) * 16 + (kq & 3);

    if (tid < NGRP) hist_g[tid] = 0;

    float acc[8] = {};
    for (int kc = 0; kc < DIM; kc += 64) {
        __syncthreads();
        {   // stage Hs + emit bf16 cast (one float4 per thread)
            const int r = tid >> 4, c4 = tid & 15;
            const float4 v = *(const float4*)(h + (size_t)(t0 + r) * DIM + kc + c4 * 4);
            *(float2*)&Hs[r][c4 * 4]     = make_float2(v.x, v.y);
            *(float2*)&Hs[r][c4 * 4 + 2] = make_float2(v.z, v.w);
            uint2 pk;
            pk.x = pack_bf16x2(v.x, v.y);
            pk.y = pack_bf16x2(v.z, v.w);
            *(uint2*)(hb + (size_t)(t0 + r) * DIM + kc + c4 * 4) = pk;
        }
        {   // stage Bs: Wg chunk (64 k x 8 g), contiguous 512 floats
            const float* src = Wg + (size_t)kc * NGRP;
            Bs[tid] = src[tid];
            Bs[tid + 256] = src[tid + 256];
        }
        __syncthreads();
#pragma unroll
        for (int kk = 0; kk < 4; ++kk) {
            const int k = kbase + kk * 4;
            const float a = Hs[t][k];
            const float4 b0 = *(const float4*)&Bs[k * 8];
            const float4 b1 = *(const float4*)&Bs[k * 8 + 4];
            acc[0] += a * b0.x; acc[1] += a * b0.y; acc[2] += a * b0.z; acc[3] += a * b0.w;
            acc[4] += a * b1.x; acc[5] += a * b1.y; acc[6] += a * b1.z; acc[7] += a * b1.w;
        }
    }
#pragma unroll
    for (int m = 0; m < 8; ++m) Sp[t][kq][m] = acc[m];
    __syncthreads();
    if (tid < 128) {
        const int tt = tid >> 3, m = tid & 7;
        float s = 0.f;
#pragma unroll
        for (int q = 0; q < 16; ++q) s += Sp[tt][q][m];
        Sg[tt][m] = s + bg[m];
    }
    __syncthreads();
    if (tid < 16) {
        int gi = 0; float best = Sg[tid][0];
#pragma unroll
        for (int g = 1; g < NGRP; ++g) {
            if (Sg[tid][g] > best) { best = Sg[tid][g]; gi = g; }
        }
        out_gidx[t0 + tid] = (float)gi;
        gidx_i[t0 + tid] = gi;
        atomicAdd(&hist_g[gi], 1);
    }
    __syncthreads();
    if (tid < NGRP) atomicAdd(&counts_g[tid], hist_g[tid]);
}

// ---------------------------------------------------------------------------
// Bucket tokens by group. Exclusive base via per-thread prefix over the 8
// counts (L1-hot). Order within a bucket is arbitrary (atomics) — benign.
// ---------------------------------------------------------------------------
__global__ __launch_bounds__(256) void scatter_g(
    const int* __restrict__ gidx_i, const int* __restrict__ counts_g,
    int* __restrict__ cursor_g, int* __restrict__ glist)
{
    const int t = blockIdx.x * 256 + threadIdx.x;
    const int g = gidx_i[t];
    int base = 0;
    for (int gg = 0; gg < g; ++gg) base += counts_g[gg];
    const int pos = base + atomicAdd(&cursor_g[g], 1);
    glist[pos] = t;
}

// ---------------------------------------------------------------------------
// Stage 2: local scores ONLY for each token's selected group (4.5x fewer
// FLOPs than all-group). Per-group gathered GEMM, 16 tokens/tile, same
// conflict-free inner loop as score_g_cast. Writes S_loc[token][m] fp32.
// ---------------------------------------------------------------------------
__global__ __launch_bounds__(256, 4) void score_loc(
    const float* __restrict__ h, const float* __restrict__ Wloc,
    const int* __restrict__ counts_g, const int* __restrict__ glist,
    float* __restrict__ S_loc)
{
    __shared__ float Hs[16][66];
    __shared__ float Bs[64 * 8];
    __shared__ float Sp[16][16][8];
    __shared__ int   tokS[16];

    const int g = blockIdx.x;
    int base = 0;
    for (int gg = 0; gg < g; ++gg) base += counts_g[gg];
    const int ng = counts_g[g];
    const float* Wl = Wloc + (size_t)g * DIM * NLOC;
    const int tid = threadIdx.x;
    const int t   = tid & 15;
    const int kq  = tid >> 4;
    const int kbase = (kq >> 2) * 16 + (kq & 3);

    for (int tile = blockIdx.y; tile * 16 < ng; tile += gridDim.y) {
        __syncthreads();   // protect prev tile's tokS/Sp consumers
        if (tid < 16) {
            const int gr = tile * 16 + tid;
            tokS[tid] = (gr < ng) ? glist[base + gr] : -1;
        }
        float acc[8] = {};
        for (int kc = 0; kc < DIM; kc += 64) {
            __syncthreads();   // tokS ready (1st) / prev k-loop reads done
            {
                const int r = tid >> 4, c4 = tid & 15;
                const int tok = tokS[r];
                float4 v = make_float4(0.f, 0.f, 0.f, 0.f);
                if (tok >= 0)
                    v = *(const float4*)(h + (size_t)tok * DIM + kc + c4 * 4);
                *(float2*)&Hs[r][c4 * 4]     = make_float2(v.x, v.y);
                *(float2*)&Hs[r][c4 * 4 + 2] = make_float2(v.z, v.w);
            }
            {
                const float* src = Wl + (size_t)kc * NLOC;
                Bs[tid] = src[tid];
                Bs[tid + 256] = src[tid + 256];
            }
            __syncthreads();
#pragma unroll
            for (int kk = 0; kk < 4; ++kk) {
                const int k = kbase + kk * 4;
                const float a = Hs[t][k];
                const float4 b0 = *(const float4*)&Bs[k * 8];
                const float4 b1 = *(const float4*)&Bs[k * 8 + 4];
                acc[0] += a * b0.x; acc[1] += a * b0.y; acc[2] += a * b0.z; acc[3] += a * b0.w;
                acc[4] += a * b1.x; acc[5] += a * b1.y; acc[6] += a * b1.z; acc[7] += a * b1.w;
            }
        }
#pragma unroll
        for (int m = 0; m < 8; ++m) Sp[t][kq][m] = acc[m];
        __syncthreads();
        if (tid < 128) {
            const int tt = tid >> 3, m = tid & 7;
            const int tok = tokS[tt];
            if (tok >= 0) {
                float s = 0.f;
#pragma unroll
                for (int q = 0; q < 16; ++q) s += Sp[tt][q][m];
                S_loc[(size_t)tok * NLOC + m] = s;
            }
        }
    }
}

// ---------------------------------------------------------------------------
// Route: top-2 + softmax + expert histogram. np first-index-wins tie rules.
// ---------------------------------------------------------------------------
__global__ __launch_bounds__(256) void route2(
    const float* __restrict__ S_loc, const int* __restrict__ gidx_i,
    float* __restrict__ out_eid, float* __restrict__ out_gate,
    int* __restrict__ ws_eids, float* __restrict__ ws_gates,
    int* __restrict__ counts_e)
{
    __shared__ int hist[NEXP];
    if (threadIdx.x < NEXP) hist[threadIdx.x] = 0;
    __syncthreads();

    const int t = blockIdx.x * 256 + threadIdx.x;
    const int gi = gidx_i[t];
    float ls[NLOC];
    const float4 l0 = *(const float4*)(S_loc + (size_t)t * NLOC);
    const float4 l1 = *(const float4*)(S_loc + (size_t)t * NLOC + 4);
    ls[0] = l0.x; ls[1] = l0.y; ls[2] = l0.z; ls[3] = l0.w;
    ls[4] = l1.x; ls[5] = l1.y; ls[6] = l1.z; ls[7] = l1.w;

    int m1 = 0; float v1 = ls[0];
#pragma unroll
    for (int m = 1; m < NLOC; ++m) { if (ls[m] > v1) { v1 = ls[m]; m1 = m; } }
    int m2 = (m1 == 0) ? 1 : 0; float v2 = ls[m2];
#pragma unroll
    for (int m = 0; m < NLOC; ++m) {
        if (m != m1 && m != ((m1 == 0) ? 1 : 0) && ls[m] > v2) { v2 = ls[m]; m2 = m; }
    }
    const float e2v = expf(v2 - v1);
    const float inv = 1.f / (1.f + e2v);
    const float g0 = inv, g1 = e2v * inv;
    const int e0 = gi * NLOC + m1, e1 = gi * NLOC + m2;

    out_eid[t * 2 + 0] = (float)e0;
    out_eid[t * 2 + 1] = (float)e1;
    out_gate[t * 2 + 0] = g0;
    out_gate[t * 2 + 1] = g1;
    ws_eids[t * 2 + 0] = e0;
    ws_eids[t * 2 + 1] = e1;
    ws_gates[t * 2 + 0] = g0;
    ws_gates[t * 2 + 1] = g1;
    atomicAdd(&hist[e0], 1);
    atomicAdd(&hist[e1], 1);

    __syncthreads();
    if (threadIdx.x < NEXP) atomicAdd(&counts_e[threadIdx.x], hist[threadIdx.x]);
}

// ---------------------------------------------------------------------------
__global__ __launch_bounds__(64) void scan_kernel(
    const int* __restrict__ counts, int* __restrict__ offsets, int* __restrict__ cursor)
{
    const int e = threadIdx.x;
    const int c = counts[e];
    int s = c;
#pragma unroll
    for (int d = 1; d < 64; d <<= 1) {
        int v = __shfl_up(s, d, 64);
        if (e >= d) s += v;
    }
    offsets[e] = s - c;
    cursor[e] = s - c;
    if (e == 63) offsets[64] = s;
}

// ---------------------------------------------------------------------------
// Scatter (token, slot-rank j) into per-expert buckets. entry = tok*2 + j.
// ---------------------------------------------------------------------------
__global__ __launch_bounds__(256) void scatter_e(
    const int* __restrict__ ws_eids, const float* __restrict__ ws_gates,
    int* __restrict__ cursor, int* __restrict__ token_list, float* __restrict__ slot_gate)
{
    const int t = blockIdx.x * 256 + threadIdx.x;
    if (t >= NTOK) return;
#pragma unroll
    for (int j = 0; j < 2; ++j) {
        const int eid = ws_eids[t * 2 + j];
        const int pos = atomicAdd(&cursor[eid], 1);
        token_list[pos] = t * 2 + j;
        slot_gate[pos] = ws_gates[t * 2 + j];
    }
}

// ---------------------------------------------------------------------------
// prep_w1: W1 fp32 [e][k][r] -> W1t bf16 [e][r][k]   (MFMA B needs k-contig)
// ---------------------------------------------------------------------------
__global__ __launch_bounds__(256) void prep_w1(
    const float* __restrict__ W1, unsigned short* __restrict__ W1t)
{
    __shared__ float Ls[64][65];
    const int e = blockIdx.x, kb = blockIdx.y;
    const float* src = W1 + (size_t)e * DIM * RANK + (size_t)kb * 64 * RANK;
#pragma unroll
    for (int it = 0; it < 4; ++it) {
        const int kk = (threadIdx.x >> 4) + it * 16;
        const int rr = (threadIdx.x & 15) * 4;
        *(float4*)&Ls[kk][rr] = *(const float4*)(src + (size_t)kk * RANK + rr);
    }
    __syncthreads();
#pragma unroll
    for (int it = 0; it < 2; ++it) {
        const int idx = threadIdx.x + it * 256;
        const int r = idx >> 3, k8 = (idx & 7) * 8;
        uint4 v;
        v.x = pack_bf16x2(Ls[k8 + 0][r], Ls[k8 + 1][r]);
        v.y = pack_bf16x2(Ls[k8 + 2][r], Ls[k8 + 3][r]);
        v.z = pack_bf16x2(Ls[k8 + 4][r], Ls[k8 + 5][r]);
        v.w = pack_bf16x2(Ls[k8 + 6][r], Ls[k8 + 7][r]);
        *(uint4*)(W1t + (size_t)e * RANK * DIM + (size_t)r * DIM + kb * 64 + k8) = v;
    }
}

// ---------------------------------------------------------------------------
// prep_w2: W2 fp32 [e][r][d] -> W2t bf16 [e][d][r]
// ---------------------------------------------------------------------------
__global__ __launch_bounds__(256) void prep_w2(
    const float* __restrict__ W2, unsigned short* __restrict__ W2t)
{
    __shared__ float Ls[64][65];
    const int e = blockIdx.x, db = blockIdx.y;
    const float* src = W2 + (size_t)e * RANK * DIM + db * 64;
#pragma unroll
    for (int it = 0; it < 4; ++it) {
        const int rr = (threadIdx.x >> 4) + it * 16;
        const int dd = (threadIdx.x & 15) * 4;
        *(float4*)&Ls[rr][dd] = *(const float4*)(src + (size_t)rr * DIM + dd);
    }
    __syncthreads();
#pragma unroll
    for (int it = 0; it < 2; ++it) {
        const int idx = threadIdx.x + it * 256;
        const int d = idx >> 3, r8 = (idx & 7) * 8;
        uint4 v;
        v.x = pack_bf16x2(Ls[r8 + 0][d], Ls[r8 + 1][d]);
        v.y = pack_bf16x2(Ls[r8 + 2][d], Ls[r8 + 3][d]);
        v.z = pack_bf16x2(Ls[r8 + 4][d], Ls[r8 + 5][d]);
        v.w = pack_bf16x2(Ls[r8 + 6][d], Ls[r8 + 7][d]);
        *(uint4*)(W2t + (size_t)e * DIM * RANK + (size_t)(db * 64 + d) * RANK + r8) = v;
    }
}

// ---------------------------------------------------------------------------
// E1 (MFMA): P[slot][r] = bf16( gate * relu(h[tok] @ W1[e]) ).
// ---------------------------------------------------------------------------
__global__ __launch_bounds__(256, 2) void e1_mfma(
    const unsigned short* __restrict__ hb, const unsigned short* __restrict__ W1t,
    const int* __restrict__ offsets, const int* __restrict__ token_list,
    const float* __restrict__ slot_gate, unsigned short* __restrict__ P)
{
    __shared__ unsigned short Hs[64 * 72];
    __shared__ unsigned short Ws[64 * 72];
    __shared__ int   tokS[64];
    __shared__ float gateS[64];

    const int e  = blockIdx.x;
    const int n0 = offsets[e];
    const int ne = offsets[e + 1] - n0;
    const unsigned short* W1te = W1t + (size_t)e * RANK * DIM;
    const int tid  = threadIdx.x;
    const int wave = tid >> 6;
    const int lane = tid & 63;
    const int tx   = lane & 15;
    const int quad = lane >> 4;

    for (int tile = blockIdx.y; tile * 64 < ne; tile += 8) {
        const int row0 = tile * 64;
        __syncthreads();
        if (tid < 64) {
            const int gr = row0 + tid;
            tokS[tid]  = (gr < ne) ? token_list[n0 + gr] : -1;
            gateS[tid] = (gr < ne) ? slot_gate[n0 + gr] : 0.f;
        }
        f32x4 acc[4] = {};
        for (int kc = 0; kc < DIM; kc += 64) {
            __syncthreads();
#pragma unroll
            for (int it = 0; it < 2; ++it) {
                const int idx = tid + it * 256;
                const int s = idx >> 3, k8 = (idx & 7) * 8;
                const int ent = tokS[s];
                uint4 v = make_uint4(0, 0, 0, 0);
                if (ent >= 0)
                    v = *(const uint4*)(hb + (size_t)(ent >> 1) * DIM + kc + k8);
                *(uint4*)(Hs + s * 72 + k8) = v;
            }
#pragma unroll
            for (int it = 0; it < 2; ++it) {
                const int idx = tid + it * 256;
                const int r = idx >> 3, k8 = (idx & 7) * 8;
                *(uint4*)(Ws + r * 72 + k8) =
                    *(const uint4*)(W1te + (size_t)r * DIM + kc + k8);
            }
            __syncthreads();
#pragma unroll
            for (int ks = 0; ks < 2; ++ks) {
                const bf16x8 a = *(const bf16x8*)(Hs + (wave * 16 + tx) * 72 + ks * 32 + quad * 8);
#pragma unroll
                for (int j = 0; j < 4; ++j) {
                    const bf16x8 b = *(const bf16x8*)(Ws + (j * 16 + tx) * 72 + ks * 32 + quad * 8);
                    acc[j] = __builtin_amdgcn_mfma_f32_16x16x32_bf16(a, b, acc[j], 0, 0, 0);
                }
            }
        }
#pragma unroll
        for (int j = 0; j < 4; ++j) {
#pragma unroll
            for (int i = 0; i < 4; ++i) {
                const int sl = wave * 16 + quad * 4 + i;
                const int gr = row0 + sl;
                if (gr < ne) {
                    const float v = fmaxf(acc[j][i], 0.f) * gateS[sl];
                    __hip_bfloat16 hv = __float2bfloat16(v);
                    P[(size_t)(n0 + gr) * RANK + j * 16 + tx] = *(unsigned short*)&hv;
                }
            }
        }
    }
}

// ---------------------------------------------------------------------------
// E2 (MFMA): C = P[slot] @ W2[e]; j=0 -> out[tok], j=1 -> contrib[tok].
// ---------------------------------------------------------------------------
__global__ __launch_bounds__(256, 2) void e2_mfma(
    const unsigned short* __restrict__ P, const unsigned short* __restrict__ W2t,
    const int* __restrict__ offsets, const int* __restrict__ token_list,
    float* __restrict__ out, float* __restrict__ contrib)
{
    __shared__ unsigned short Ps[64 * 72];
    __shared__ unsigned short W2s[64 * 72];
    __shared__ int tokS[64];

    const int e = blockIdx.x;
    const int colbase = blockIdx.y * 64;
    const int n0 = offsets[e];
    const int ne = offsets[e + 1] - n0;
    const unsigned short* W2te = W2t + (size_t)e * DIM * RANK;
    const int tid  = threadIdx.x;
    const int wave = tid >> 6;
    const int lane = tid & 63;
    const int tx   = lane & 15;
    const int quad = lane >> 4;

#pragma unroll
    for (int it = 0; it < 2; ++it) {
        const int idx = tid + it * 256;
        const int d = idx >> 3, r8 = (idx & 7) * 8;
        *(uint4*)(W2s + d * 72 + r8) =
            *(const uint4*)(W2te + (size_t)(colbase + d) * RANK + r8);
    }

    for (int tile = blockIdx.z; tile * 64 < ne; tile += 4) {
        const int row0 = tile * 64;
        __syncthreads();
        if (tid < 64) {
            const int gr = row0 + tid;
            tokS[tid] = (gr < ne) ? token_list[n0 + gr] : -1;
        }
#pragma unroll
        for (int it = 0; it < 2; ++it) {
            const int idx = tid + it * 256;
            const int s = idx >> 3, r8 = (idx & 7) * 8;
            const int gr = row0 + s;
            uint4 v = make_uint4(0, 0, 0, 0);
            if (gr < ne) v = *(const uint4*)(P + (size_t)(n0 + gr) * RANK + r8);
            *(uint4*)(Ps + s * 72 + r8) = v;
        }
        __syncthreads();
        f32x4 acc[4] = {};
#pragma unroll
        for (int ks = 0; ks < 2; ++ks) {
            const bf16x8 a = *(const bf16x8*)(Ps + (wave * 16 + tx) * 72 + ks * 32 + quad * 8);
#pragma unroll
            for (int j = 0; j < 4; ++j) {
                const bf16x8 b = *(const bf16x8*)(W2s + (j * 16 + tx) * 72 + ks * 32 + quad * 8);
                acc[j] = __builtin_amdgcn_mfma_f32_16x16x32_bf16(a, b, acc[j], 0, 0, 0);
            }
        }
#pragma unroll
        for (int i = 0; i < 4; ++i) {
            const int sl = wave * 16 + quad * 4 + i;
            const int ent = tokS[sl];
            if (ent >= 0) {
                float* base = (ent & 1) ? contrib : out;
                float* op = base + (size_t)(ent >> 1) * DIM + colbase;
#pragma unroll
                for (int j = 0; j < 4; ++j)
                    op[j * 16 + tx] = acc[j][i];
            }
        }
    }
}

// ---------------------------------------------------------------------------
__global__ __launch_bounds__(256) void combine_kernel(
    const float* __restrict__ contrib, float* __restrict__ out)
{
    const size_t i = (size_t)blockIdx.x * 256 + threadIdx.x;
    float4 a = ((const float4*)out)[i];
    const float4 b = ((const float4*)contrib)[i];
    a.x += b.x; a.y += b.y; a.z += b.z; a.w += b.w;
    ((float4*)out)[i] = a;
}

// ---------------------------------------------------------------------------
extern "C" void kernel_launch(void* const* d_in, const int* in_sizes, int n_in,
                              void* d_out, int out_size, void* d_ws, size_t ws_size,
                              hipStream_t stream)
{
    const float* h    = (const float*)d_in[0];
    const float* Wg   = (const float*)d_in[1];
    const float* bg   = (const float*)d_in[2];
    const float* Wloc = (const float*)d_in[3];
    const float* W1   = (const float*)d_in[4];
    const float* W2   = (const float*)d_in[5];

    float* out_f    = (float*)d_out;
    float* out_main = out_f;
    float* out_eid  = out_f + (size_t)NTOK * DIM;
    float* out_gate = out_eid + (size_t)NTOK * 2;
    float* out_gidx = out_gate + (size_t)NTOK * 2;

    int* ws_i        = (int*)d_ws;
    int* counts_e    = ws_i;                  // [0,64)
    int* offsets_e   = ws_i + 64;             // [64,129)
    int* cursor_e    = ws_i + 192;            // [192,256)
    int* counts_g    = ws_i + 256;            // [256,264)
    int* cursor_g    = ws_i + 264;            // [264,272)
    int* gidx_i      = ws_i + 512;            // [512,8704)
    int* glist       = ws_i + 8704;           // 8192
    int* ws_eids     = ws_i + 16896;          // 16384
    int* token_list  = ws_i + 33280;          // 16384
    float* ws_f      = (float*)(ws_i + 49664);
    float* ws_gates  = ws_f;                  // 16384
    float* slot_gate = ws_f + 16384;          // 16384
    float* S_loc     = ws_f + 2 * 16384;      // 65536
    unsigned short* P_h = (unsigned short*)(ws_f + 2 * 16384 + 65536);  // 2 MB
    unsigned short* W1t = P_h + (size_t)16384 * RANK;                   // 8 MB
    unsigned short* W2t = W1t + (size_t)NEXP * RANK * DIM;              // 8 MB
    float* contrib      = (float*)(W2t + (size_t)NEXP * DIM * RANK);    // 32 MB
    // hb (16.8 MB) aliases contrib: written by score_g_cast, read by e1,
    // clobbered by e2's contrib stores (e1 complete by then; stream-serial).
    unsigned short* hb = (unsigned short*)contrib;

    hipMemsetAsync(ws_i, 0, 272 * sizeof(int), stream);

    prep_w1<<<dim3(NEXP, 16), 256, 0, stream>>>(W1, W1t);
    prep_w2<<<dim3(NEXP, 16), 256, 0, stream>>>(W2, W2t);
    score_g_cast<<<NTOK / 16, 256, 0, stream>>>(h, Wg, bg, hb,
        out_gidx, gidx_i, counts_g);
    scatter_g<<<NTOK / 256, 256, 0, stream>>>(gidx_i, counts_g, cursor_g, glist);
    score_loc<<<dim3(NGRP, 64), 256, 0, stream>>>(h, Wloc, counts_g, glist, S_loc);
    route2<<<NTOK / 256, 256, 0, stream>>>(S_loc, gidx_i,
        out_eid, out_gate, ws_eids, ws_gates, counts_e);
    scan_kernel<<<1, 64, 0, stream>>>(counts_e, offsets_e, cursor_e);
    scatter_e<<<NTOK / 256, 256, 0, stream>>>(ws_eids, ws_gates, cursor_e,
        token_list, slot_gate);
    e1_mfma<<<dim3(NEXP, 8), 256, 0, stream>>>(hb, W1t, offsets_e, token_list,
        slot_gate, P_h);
    e2_mfma<<<dim3(NEXP, 16, 4), 256, 0, stream>>>(P_h, W2t, offsets_e, token_list,
        out_main, contrib);
    combine_kernel<<<(NTOK * DIM / 4) / 256, 256, 0, stream>>>(contrib, out_main);
}